// Round 2
// baseline (283.925 us; speedup 1.0000x reference)
//
#include <hip/hip_runtime.h>
#include <hip/hip_bf16.h>
#include <cmath>

#define T_SEQ 2048
#define NHEADS 16
#define DHEAD 64
#define DMODEL 1024
#define CQKV 3072

typedef __attribute__((ext_vector_type(8))) short short8;
typedef __attribute__((ext_vector_type(8))) __bf16 bf16x8;
typedef __attribute__((ext_vector_type(4))) float floatx4;

#define LDS_CAST(p) ((__attribute__((address_space(3))) void*)(p))
#define GLB_CAST(p) ((const __attribute__((address_space(1))) void*)(p))

static __device__ __forceinline__ floatx4 mfma_bf16(short8 a, short8 b, floatx4 c) {
  return __builtin_amdgcn_mfma_f32_16x16x32_bf16(
      __builtin_bit_cast(bf16x8, a), __builtin_bit_cast(bf16x8, b), c, 0, 0, 0);
}

// fp32 -> bf16 round-to-nearest-even, bit carrier = short
static __device__ __forceinline__ short f2bf(float f) {
  union { float f; unsigned u; } x; x.f = f;
  unsigned r = x.u + 0x7FFFu + ((x.u >> 16) & 1u);
  return (short)(r >> 16);
}

static __device__ __forceinline__ float bf2f(short s) {
  return __builtin_bit_cast(float, ((unsigned)(unsigned short)s) << 16);
}

static __device__ __forceinline__ float exp2_(float x) {
#if __has_builtin(__builtin_amdgcn_exp2f)
  return __builtin_amdgcn_exp2f(x);
#else
  return exp2f(x);
#endif
}

// bf16 vs fp32 input sniff (round-1 notes). 16-of-32 exponent vote.
static __device__ __forceinline__ bool sniff_is_bf16(const unsigned* __restrict__ x) {
  int cnt = 0;
#pragma unroll
  for (int i = 0; i < 32; ++i) {
    unsigned e = (x[i] >> 7) & 0xFFu;
    cnt += (e >= 0x70u && e <= 0x8Fu) ? 1 : 0;
  }
  return cnt >= 16;
}

static __device__ __forceinline__ short8 load8f32(const char* p, size_t idx) {
  const float4* f = (const float4*)(p + idx * 4);
  float4 a = f[0], b = f[1];
  short8 r;
  r[0] = f2bf(a.x); r[1] = f2bf(a.y); r[2] = f2bf(a.z); r[3] = f2bf(a.w);
  r[4] = f2bf(b.x); r[5] = f2bf(b.y); r[6] = f2bf(b.z); r[7] = f2bf(b.w);
  return r;
}

// ---- preprocessing: x -> bf16 copy/convert --------------------------------
__global__ __launch_bounds__(256) void conv_x(const char* __restrict__ x,
                                              short* __restrict__ o, int n,
                                              const unsigned* __restrict__ xs) {
  const bool isbf = sniff_is_bf16(xs);
  const int i = (blockIdx.x * 256 + threadIdx.x) * 8;
  if (i >= n) return;
  if (isbf) *(short8*)(o + i) = *(const short8*)((const short*)x + i);
  else      *(short8*)(o + i) = load8f32(x, (size_t)i);
}

// ---- preprocessing: W [K][N] -> W^T [N][K] bf16 ---------------------------
__global__ __launch_bounds__(256) void tpose(const char* __restrict__ w,
                                             short* __restrict__ wt, int K, int N,
                                             const unsigned* __restrict__ xs) {
  const bool isbf = sniff_is_bf16(xs);
  __shared__ short tile[32][33];
  const int n0 = blockIdx.x * 32, k0 = blockIdx.y * 32;
  const int tx = threadIdx.x & 31, ty = threadIdx.x >> 5;  // 32 x 8
#pragma unroll
  for (int i = 0; i < 4; ++i) {
    const int r = ty * 4 + i;
    const size_t off = (size_t)(k0 + r) * N + n0 + tx;
    tile[r][tx] = isbf ? ((const short*)w)[off] : f2bf(((const float*)w)[off]);
  }
  __syncthreads();
#pragma unroll
  for (int i = 0; i < 4; ++i) {
    const int r = ty * 4 + i;
    wt[(size_t)(n0 + r) * K + k0 + tx] = tile[tx][r];
  }
}

// ---- GEMM: C = A @ Bt^T, 256x256 tile, BK=64, 8-phase counted-vmcnt -------
// T3+T4+T5 template (learn_hip m201): 512 thr / 8 waves (2M x 4N), 128 KiB
// double-buffered LDS, raw s_barrier (NOT __syncthreads -> no vmcnt(0) drain),
// s_waitcnt vmcnt(4) once per K-tile, setprio(1) around each 16-MFMA cluster.
// LDS layout: rows of 64 shorts (128B), 16B chunk j of row R at slot j^(R&7)
// (the conflict-free swizzle proven in the gemm128 kernel; staged via
// pre-swizzled global source addresses, linear global_load_lds dest).
//
// Stage schedule per K-tile t (compute buffer cb=t&1, other nb):
//   ph0: ds A(mh0)+B(nh0,kept in regs); stage A-half0(t+1)->nb
//   ph1: ds B(nh1);                     stage A-half1(t+1)->nb
//   ph2: ds A(mh1);                     stage B-half0(t+2)->cb   (B reads of cb
//   ph3: (regs only, uses kept B(nh0)); stage B-half1(t+2)->cb    done at ph1)
//        s_waitcnt vmcnt(4)   <- confirms everything through A1(t+1); only the
//                                4 loads of B(t+2) stay in flight across barriers
// WAR safety: every stage into a region is issued >=1 post-MFMA barrier after
// that region's last ds_read completed (A of a buffer done by ph2, B by ph1).
//
// mode 0: C bf16 row-major [M,N]
// mode 1: C dtype per sniff (bf16 in -> bf16 out, fp32 in -> fp32 out)
// mode 2: QKV split: cols [0,2048) -> qk [M,2048]; cols [2048,3072) -> vT.
__global__ __launch_bounds__(512) void gemm256(const short* __restrict__ A,
                                               const short* __restrict__ Bt,
                                               void* __restrict__ C,
                                               short* __restrict__ C2,
                                               int M, int N, int K, int mode,
                                               const unsigned* __restrict__ xs) {
  const bool out_f32 = (mode == 1) ? !sniff_is_bf16(xs) : false;

  __shared__ short as[2][256 * 64];  // 64 KiB
  __shared__ short bs[2][256 * 64];  // 64 KiB
  const int tid = threadIdx.x;
  const int wid = tid >> 6, lane = tid & 63;
  const int quad = lane >> 4, l16 = lane & 15;
  const int wm = wid >> 2, wn = wid & 3;  // 2 x 4 wave grid, each owns 128x64

  // XCD-aware bijective blockIdx swizzle (all our grids are multiples of 8)
  const int gx = (int)gridDim.x;
  const int nwg = gx * (int)gridDim.y;
  int bid = (int)blockIdx.y * gx + (int)blockIdx.x;
  bid = (bid & 7) * (nwg >> 3) + (bid >> 3);
  const int m0 = (bid / gx) * 256;
  const int n0 = (bid % gx) * 256;

  const int srl = lane >> 3;               // staging: row within 8-row group
  const int sch = ((lane & 7) ^ srl) * 8;  // XOR-swizzled source chunk (shorts)
  const int NT = K >> 6;

  // one half-tile (128 rows x 64 shorts = 16 KiB) per call: 2 loads/thread
#define STAGE_A(t, h, b)                                                          \
  do {                                                                            \
    const int kt_ = (t) << 6;                                                     \
    _Pragma("unroll") for (int j_ = 0; j_ < 2; ++j_) {                            \
      const int row_ = (h) * 128 + j_ * 64 + wid * 8;                             \
      const short* g_ = A + (size_t)(m0 + row_ + srl) * K + kt_ + sch;            \
      __builtin_amdgcn_global_load_lds(GLB_CAST(g_), LDS_CAST(&as[(b)][row_ * 64]), 16, 0, 0); \
    }                                                                             \
  } while (0)

#define STAGE_B(t, h, b)                                                          \
  do {                                                                            \
    const int kt_ = (t) << 6;                                                     \
    _Pragma("unroll") for (int j_ = 0; j_ < 2; ++j_) {                            \
      const int row_ = (h) * 128 + j_ * 64 + wid * 8;                             \
      const short* g_ = Bt + (size_t)(n0 + row_ + srl) * K + kt_ + sch;           \
      __builtin_amdgcn_global_load_lds(GLB_CAST(g_), LDS_CAST(&bs[(b)][row_ * 64]), 16, 0, 0); \
    }                                                                             \
  } while (0)

#define SLOT_(kc) ((((kc) * 4 + quad) ^ (l16 & 7)) * 8)

#define LOAD_A(dst, mh, b)                                                        \
  do {                                                                            \
    _Pragma("unroll") for (int mf_ = 0; mf_ < 4; ++mf_)                           \
    _Pragma("unroll") for (int kc_ = 0; kc_ < 2; ++kc_)                           \
      dst[mf_][kc_] = *(const short8*)&as[(b)][(wm * 128 + (mh) * 64 + mf_ * 16 + l16) * 64 + SLOT_(kc_)]; \
  } while (0)

#define LOAD_B(dst, nh, b)                                                        \
  do {                                                                            \
    _Pragma("unroll") for (int nf_ = 0; nf_ < 2; ++nf_)                           \
    _Pragma("unroll") for (int kc_ = 0; kc_ < 2; ++kc_)                           \
      dst[nf_][kc_] = *(const short8*)&bs[(b)][(wn * 64 + (nh) * 32 + nf_ * 16 + l16) * 64 + SLOT_(kc_)]; \
  } while (0)

#define QMFMA(afrag, bfrag, mh, nh)                                               \
  do {                                                                            \
    __builtin_amdgcn_s_setprio(1);                                                \
    _Pragma("unroll") for (int mf_ = 0; mf_ < 4; ++mf_)                           \
    _Pragma("unroll") for (int nf_ = 0; nf_ < 2; ++nf_)                           \
    _Pragma("unroll") for (int kc_ = 0; kc_ < 2; ++kc_)                           \
      acc[(mh) * 4 + mf_][(nh) * 2 + nf_] =                                       \
          mfma_bf16(afrag[mf_][kc_], bfrag[nf_][kc_], acc[(mh) * 4 + mf_][(nh) * 2 + nf_]); \
    __builtin_amdgcn_s_setprio(0);                                                \
  } while (0)

  // raw barrier fenced against scheduler motion (rule 18-style insurance)
#define BAR_()                                                                    \
  do {                                                                            \
    __builtin_amdgcn_sched_barrier(0);                                            \
    __builtin_amdgcn_s_barrier();                                                 \
    __builtin_amdgcn_sched_barrier(0);                                            \
  } while (0)

  // counted vmcnt wait, fenced so nothing dependent is hoisted above it
#define WAITV_(n)                                                                 \
  do {                                                                            \
    asm volatile("s_waitcnt vmcnt(" #n ")" ::: "memory");                         \
    __builtin_amdgcn_sched_barrier(0);                                            \
  } while (0)

  const floatx4 zero4 = {0.f, 0.f, 0.f, 0.f};
  floatx4 acc[8][4];
#pragma unroll
  for (int i = 0; i < 8; ++i)
#pragma unroll
    for (int j = 0; j < 4; ++j) acc[i][j] = zero4;

  // ---- prologue: issue order must match steady-state so vmcnt counts work
  STAGE_B(0, 0, 0); STAGE_B(0, 1, 0);
  STAGE_A(0, 0, 0); STAGE_A(0, 1, 0);
  STAGE_B(1, 0, 1); STAGE_B(1, 1, 1);
  WAITV_(4);  // tile0 complete, B(1)'s 4 loads stay in flight
  BAR_();

  short8 afr[4][2], bf0[2][2], bf1[2][2];

  for (int t = 0; t < NT; ++t) {
    const int cb = t & 1, nb = cb ^ 1;
    const int tA = (t + 1 < NT) ? t + 1 : NT - 1;  // clamped tail keeps vmcnt
    const int tB = (t + 2 < NT) ? t + 2 : NT - 1;  // counts uniform (junk-safe)

    // ---- phase 0: quadrant (mh0,nh0)
    LOAD_A(afr, 0, cb);
    LOAD_B(bf0, 0, cb);   // kept in regs through phase 3
    STAGE_A(tA, 0, nb);
    BAR_();
    QMFMA(afr, bf0, 0, 0);
    BAR_();

    // ---- phase 1: quadrant (mh0,nh1)
    LOAD_B(bf1, 1, cb);
    STAGE_A(tA, 1, nb);
    BAR_();
    QMFMA(afr, bf1, 0, 1);
    BAR_();

    // ---- phase 2: quadrant (mh1,nh1)
    LOAD_A(afr, 1, cb);
    STAGE_B(tB, 0, cb);   // cb's B fully read by end of phase 1
    BAR_();
    QMFMA(afr, bf1, 1, 1);
    BAR_();

    // ---- phase 3: quadrant (mh1,nh0) -- no ds_read, uses kept bf0
    STAGE_B(tB, 1, cb);
    WAITV_(4);  // next tile confirmed; only B(t+2) stays in flight
    BAR_();
    QMFMA(afr, bf0, 1, 0);
    BAR_();
  }
  // drain tail junk-stage DMAs before LDS can be handed to the next block
  asm volatile("s_waitcnt vmcnt(0)" ::: "memory");
  __builtin_amdgcn_sched_barrier(0);

  // ---- epilogue
  const int row0 = m0 + wm * 128 + quad * 4;
  const int col0 = n0 + wn * 64 + l16;
  if (mode == 2 && n0 >= 2048) {
    // V part -> transposed vT[(b*16+h)*64+d][t]
#pragma unroll
    for (int mi = 0; mi < 8; ++mi)
#pragma unroll
      for (int ni = 0; ni < 4; ++ni)
#pragma unroll
        for (int r = 0; r < 4; ++r) {
          const int row = row0 + mi * 16 + r;
          const int col = col0 + ni * 16;
          const int d = col & 63, hh = (col >> 6) - 32;
          const int bb = row >> 11, tq = row & 2047;
          C2[((size_t)(bb * 16 + hh) * 64 + d) * T_SEQ + tq] = f2bf(acc[mi][ni][r]);
        }
  } else {
    const int outN = (mode == 2) ? 2048 : N;
#pragma unroll
    for (int mi = 0; mi < 8; ++mi)
#pragma unroll
      for (int ni = 0; ni < 4; ++ni)
#pragma unroll
        for (int r = 0; r < 4; ++r) {
          const size_t off = (size_t)(row0 + mi * 16 + r) * outN + col0 + ni * 16;
          if (out_f32) ((float*)C)[off] = acc[mi][ni][r];
          else         ((short*)C)[off] = f2bf(acc[mi][ni][r]);
        }
  }
#undef STAGE_A
#undef STAGE_B
#undef SLOT_
#undef LOAD_A
#undef LOAD_B
#undef QMFMA
#undef BAR_
#undef WAITV_
}

// ---- flash attention (round-6 validated version, unchanged) ---------------
// qk [b*2048+t][2048] (Q cols 0..1023, K cols 1024..2047), vT [(b*16+h)*64+d][t].
// Block = 4 waves x 16 queries; BK=64. K/V tiles shared by all 4 waves.
__global__ __launch_bounds__(256) void attn(const short* __restrict__ qk,
                                            const short* __restrict__ vT,
                                            short* __restrict__ y) {
  __shared__ short ks[64 * 64];    // [key][d], 8 chunks/row XOR-swizzled
  __shared__ short vs[64 * 64];    // [d][key], same swizzle
  __shared__ short ps[4][16][72];  // per-wave P [q][key]
  const int tid = threadIdx.x;
  const int wid = tid >> 6, lane = tid & 63;
  const int quad = lane >> 4, l16 = lane & 15;
  const int b = blockIdx.x >> 4, h = blockIdx.x & 15;
  const int q0 = ((int)gridDim.y - 1 - (int)blockIdx.y) * 64;  // heavy blocks first
  const int qw0 = q0 + wid * 16;

  const short* qbase = qk + (size_t)b * T_SEQ * 2048 + h * DHEAD;
  const short* kbase = qbase + DMODEL;
  const short* vtb = vT + (size_t)(b * NHEADS + h) * DHEAD * T_SEQ;
  const float SC = 0.18033688011112042f;  // 0.125 * log2(e), folded into Q

  // Q fragments (A-layout m=l16, k=quad*8+j), pre-scaled by SC
  short8 aq[2];
#pragma unroll
  for (int kc = 0; kc < 2; ++kc) {
    short8 raw = *(const short8*)(qbase + (size_t)(qw0 + l16) * 2048 + kc * 32 + quad * 8);
#pragma unroll
    for (int j = 0; j < 8; ++j) aq[kc][j] = f2bf(bf2f(raw[j]) * SC);
  }

  const floatx4 zero4 = {0.f, 0.f, 0.f, 0.f};
  floatx4 o[4], lacc = zero4;  // lacc: row-sum via ones-MFMA
#pragma unroll
  for (int i = 0; i < 4; ++i) o[i] = zero4;
  const short8 ones8 = {0x3F80, 0x3F80, 0x3F80, 0x3F80, 0x3F80, 0x3F80, 0x3F80, 0x3F80};

  // staging lane map: row = i*32 + wid*8 + (lane>>3), chunk = (lane&7) ^ (row&7)
  const int srl = lane >> 3;
  const int sch = ((lane & 7) ^ srl) * 8;

  const int kend = q0 + 64;
  for (int kt = 0; kt < kend; kt += 64) {
    __syncthreads();  // prev iteration's LDS readers done
#pragma unroll
    for (int i = 0; i < 2; ++i) {
      const int row = i * 32 + wid * 8 + srl;
      const short* gk = kbase + (size_t)(kt + row) * 2048 + sch;
      const short* gv = vtb + (size_t)row * T_SEQ + kt + sch;
      __builtin_amdgcn_global_load_lds(GLB_CAST(gk), LDS_CAST(ks + (i * 32 + wid * 8) * 64), 16, 0, 0);
      __builtin_amdgcn_global_load_lds(GLB_CAST(gv), LDS_CAST(vs + (i * 32 + wid * 8) * 64), 16, 0, 0);
    }
    __syncthreads();  // DMA drained

    // S = Q K^T : 16q x 64key per wave; B-frag chunk kc*4+quad at swizzled slot
    floatx4 s[4];
#pragma unroll
    for (int nt = 0; nt < 4; ++nt) {
      s[nt] = zero4;
#pragma unroll
      for (int kc = 0; kc < 2; ++kc) {
        const int slot = ((kc * 4 + quad) ^ (l16 & 7)) * 8;
        const short8 bk = *(const short8*)&ks[(nt * 16 + l16) * 64 + slot];
        s[nt] = mfma_bf16(aq[kc], bk, s[nt]);
      }
    }

    // max-free softmax: p = 2^s; zero masked keys (diagonal tiles only)
    const bool full = (kt + 63 <= qw0);  // wave-uniform
#pragma unroll
    for (int nt = 0; nt < 4; ++nt)
#pragma unroll
      for (int r = 0; r < 4; ++r) {
        float p = exp2_(s[nt][r]);
        if (!full) {
          const int key = kt + nt * 16 + l16;
          const int q = qw0 + quad * 4 + r;
          p = (key <= q) ? p : 0.f;
        }
        s[nt][r] = p;
      }

    // P (C-layout) -> per-wave LDS [q][key] (wave-internal, no barrier)
#pragma unroll
    for (int nt = 0; nt < 4; ++nt)
#pragma unroll
      for (int r = 0; r < 4; ++r)
        ps[wid][quad * 4 + r][nt * 16 + l16] = f2bf(s[nt][r]);

    // O += P V ; l += P 1
#pragma unroll
    for (int kc = 0; kc < 2; ++kc) {
      const short8 ap = *(const short8*)&ps[wid][l16][kc * 32 + quad * 8];
      lacc = mfma_bf16(ap, ones8, lacc);
#pragma unroll
      for (int d4 = 0; d4 < 4; ++d4) {
        const int slot = ((kc * 4 + quad) ^ (l16 & 7)) * 8;
        const short8 bv = *(const short8*)&vs[(d4 * 16 + l16) * 64 + slot];
        o[d4] = mfma_bf16(ap, bv, o[d4]);
      }
    }
  }

  // epilogue: O /= l
  floatx4 inv;
#pragma unroll
  for (int r = 0; r < 4; ++r) inv[r] = 1.0f / lacc[r];
#pragma unroll
  for (int d4 = 0; d4 < 4; ++d4)
#pragma unroll
    for (int r = 0; r < 4; ++r) {
      const int q = qw0 + quad * 4 + r;
      y[(size_t)(b * T_SEQ + q) * DMODEL + h * DHEAD + d4 * 16 + l16] =
          f2bf(o[d4][r] * inv[r]);
    }
}

extern "C" void kernel_launch(void* const* d_in, const int* in_sizes, int n_in,
                              void* d_out, int out_size, void* d_ws, size_t ws_size,
                              hipStream_t stream) {
  const char* x = (const char*)d_in[0];       // [4,2048,1024] fp32 (or bf16)
  const char* w_qkv = (const char*)d_in[1];   // [1024,3072]
  const char* w_proj = (const char*)d_in[2];  // [1024,1024]
  const unsigned* xs = (const unsigned*)d_in[0];

  // ws: qk(33.6M) | vT(16.8M) | wqkvT(6.3M) | wprojT(2.1M) | xbf=ybuf(16.8M) = 75.5MB
  short* qk = (short*)d_ws;                          // 8192*2048
  short* vTb = qk + (size_t)8192 * 2048;             // 64*64*2048
  short* wqkvT = vTb + (size_t)64 * 64 * 2048;       // 3072*1024
  short* wprojT = wqkvT + (size_t)3072 * 1024;       // 1024*1024
  short* xbf = wprojT + (size_t)1024 * 1024;         // 8192*1024
  short* ybuf = xbf;                                 // alias: xbf dead after gemm1

  conv_x<<<8192 * 1024 / (256 * 8), 256, 0, stream>>>(x, xbf, 8192 * 1024, xs);
  {
    dim3 g1(3072 / 32, 1024 / 32);
    tpose<<<g1, 256, 0, stream>>>(w_qkv, wqkvT, 1024, 3072, xs);
    dim3 g2(1024 / 32, 1024 / 32);
    tpose<<<g2, 256, 0, stream>>>(w_proj, wprojT, 1024, 1024, xs);
  }
  {  // qkv projection with split epilogue: Q,K -> qk ; V -> vT (transposed)
    dim3 grid(3072 / 256, 8192 / 256);  // 12 x 32 = 384 blocks (384 % 8 == 0)
    gemm256<<<grid, 512, 0, stream>>>(xbf, wqkvT, qk, vTb, 8192, 3072, 1024, 2, xs);
  }
  {
    dim3 grid(4 * NHEADS, T_SEQ / 64);
    attn<<<grid, 256, 0, stream>>>(qk, vTb, ybuf);
  }
  {
    dim3 grid(1024 / 256, 8192 / 256);  // 4 x 32 = 128 blocks (128 % 8 == 0)
    gemm256<<<grid, 512, 0, stream>>>(ybuf, wprojT, d_out, nullptr, 8192, 1024, 1024, 1, xs);
  }
}

// Round 3
// 282.855 us; speedup vs baseline: 1.0038x; 1.0038x over previous
//
#include <hip/hip_runtime.h>
#include <hip/hip_bf16.h>
#include <cmath>

#define T_SEQ 2048
#define NHEADS 16
#define DHEAD 64
#define DMODEL 1024
#define CQKV 3072

typedef __attribute__((ext_vector_type(8))) short short8;
typedef __attribute__((ext_vector_type(8))) __bf16 bf16x8;
typedef __attribute__((ext_vector_type(4))) float floatx4;

#define LDS_CAST(p) ((__attribute__((address_space(3))) void*)(p))
#define GLB_CAST(p) ((const __attribute__((address_space(1))) void*)(p))

static __device__ __forceinline__ floatx4 mfma_bf16(short8 a, short8 b, floatx4 c) {
  return __builtin_amdgcn_mfma_f32_16x16x32_bf16(
      __builtin_bit_cast(bf16x8, a), __builtin_bit_cast(bf16x8, b), c, 0, 0, 0);
}

// fp32 -> bf16 round-to-nearest-even, bit carrier = short
static __device__ __forceinline__ short f2bf(float f) {
  union { float f; unsigned u; } x; x.f = f;
  unsigned r = x.u + 0x7FFFu + ((x.u >> 16) & 1u);
  return (short)(r >> 16);
}

static __device__ __forceinline__ float bf2f(short s) {
  return __builtin_bit_cast(float, ((unsigned)(unsigned short)s) << 16);
}

static __device__ __forceinline__ float exp2_(float x) {
#if __has_builtin(__builtin_amdgcn_exp2f)
  return __builtin_amdgcn_exp2f(x);
#else
  return exp2f(x);
#endif
}

// bf16 vs fp32 input sniff (round-1 notes). 16-of-32 exponent vote.
static __device__ __forceinline__ bool sniff_is_bf16(const unsigned* __restrict__ x) {
  int cnt = 0;
#pragma unroll
  for (int i = 0; i < 32; ++i) {
    unsigned e = (x[i] >> 7) & 0xFFu;
    cnt += (e >= 0x70u && e <= 0x8Fu) ? 1 : 0;
  }
  return cnt >= 16;
}

static __device__ __forceinline__ short8 load8f32(const char* p, size_t idx) {
  const float4* f = (const float4*)(p + idx * 4);
  float4 a = f[0], b = f[1];
  short8 r;
  r[0] = f2bf(a.x); r[1] = f2bf(a.y); r[2] = f2bf(a.z); r[3] = f2bf(a.w);
  r[4] = f2bf(b.x); r[5] = f2bf(b.y); r[6] = f2bf(b.z); r[7] = f2bf(b.w);
  return r;
}

// ---- preprocessing: x -> bf16 copy/convert --------------------------------
__global__ __launch_bounds__(256) void conv_x(const char* __restrict__ x,
                                              short* __restrict__ o, int n,
                                              const unsigned* __restrict__ xs) {
  const bool isbf = sniff_is_bf16(xs);
  const int i = (blockIdx.x * 256 + threadIdx.x) * 8;
  if (i >= n) return;
  if (isbf) *(short8*)(o + i) = *(const short8*)((const short*)x + i);
  else      *(short8*)(o + i) = load8f32(x, (size_t)i);
}

// ---- preprocessing: W [K][N] -> W^T [N][K] bf16 ---------------------------
__global__ __launch_bounds__(256) void tpose(const char* __restrict__ w,
                                             short* __restrict__ wt, int K, int N,
                                             const unsigned* __restrict__ xs) {
  const bool isbf = sniff_is_bf16(xs);
  __shared__ short tile[32][33];
  const int n0 = blockIdx.x * 32, k0 = blockIdx.y * 32;
  const int tx = threadIdx.x & 31, ty = threadIdx.x >> 5;  // 32 x 8
#pragma unroll
  for (int i = 0; i < 4; ++i) {
    const int r = ty * 4 + i;
    const size_t off = (size_t)(k0 + r) * N + n0 + tx;
    tile[r][tx] = isbf ? ((const short*)w)[off] : f2bf(((const float*)w)[off]);
  }
  __syncthreads();
#pragma unroll
  for (int i = 0; i < 4; ++i) {
    const int r = ty * 4 + i;
    wt[(size_t)(n0 + r) * K + k0 + tx] = tile[tx][r];
  }
}

// ---- GEMM: C = A @ Bt^T, 256x256 tile, BK=64, 8-phase counted-vmcnt -------
// T3+T4+T5 template (learn_hip m201), UNPINNED (round-2 post-mortem: the
// sched_barrier(0) wrappers were an m141-class regression -- removed).
// Discipline now matches the verified template exactly:
//   phase = { ds_reads; stage; [vmcnt(4) at ph3]; s_barrier;
//             s_waitcnt lgkmcnt(0)  <- data wait AND motion fence;
//             setprio(1); MFMA x16; setprio(0); s_barrier }
// The lgkmcnt(0) asm carries a "memory" clobber so no ds_read can hoist
// above the barrier that guarantees cross-wave DMA visibility.
//
// Stage schedule per K-tile t (compute buffer cb=t&1, other nb):
//   ph0: ds A(mh0)+B(nh0,kept in regs); stage A-half0(t+1)->nb
//   ph1: ds B(nh1);                     stage A-half1(t+1)->nb
//   ph2: ds A(mh1);                     stage B-half0(t+2)->cb   (B reads of cb
//   ph3: (regs only, uses kept B(nh0)); stage B-half1(t+2)->cb    done at ph1)
//        s_waitcnt vmcnt(4)   <- confirms everything through A1(t+1); only the
//                                4 loads of B(t+2) stay in flight across barriers
//
// mode 0: C bf16 row-major [M,N]
// mode 1: C dtype per sniff (bf16 in -> bf16 out, fp32 in -> fp32 out)
// mode 2: QKV split: cols [0,2048) -> qk [M,2048]; cols [2048,3072) -> vT.
__global__ __launch_bounds__(512) void gemm256(const short* __restrict__ A,
                                               const short* __restrict__ Bt,
                                               void* __restrict__ C,
                                               short* __restrict__ C2,
                                               int M, int N, int K, int mode,
                                               const unsigned* __restrict__ xs) {
  const bool out_f32 = (mode == 1) ? !sniff_is_bf16(xs) : false;

  __shared__ short as[2][256 * 64];  // 64 KiB
  __shared__ short bs[2][256 * 64];  // 64 KiB
  const int tid = threadIdx.x;
  const int wid = tid >> 6, lane = tid & 63;
  const int quad = lane >> 4, l16 = lane & 15;
  const int wm = wid >> 2, wn = wid & 3;  // 2 x 4 wave grid, each owns 128x64

  // XCD-aware bijective blockIdx swizzle (all our grids are multiples of 8)
  const int gx = (int)gridDim.x;
  const int nwg = gx * (int)gridDim.y;
  int bid = (int)blockIdx.y * gx + (int)blockIdx.x;
  bid = (bid & 7) * (nwg >> 3) + (bid >> 3);
  const int m0 = (bid / gx) * 256;
  const int n0 = (bid % gx) * 256;

  const int srl = lane >> 3;               // staging: row within 8-row group
  const int sch = ((lane & 7) ^ srl) * 8;  // XOR-swizzled source chunk (shorts)
  const int NT = K >> 6;

  // one half-tile (128 rows x 64 shorts = 16 KiB) per call: 2 loads/thread
#define STAGE_A(t, h, b)                                                          \
  do {                                                                            \
    const int kt_ = (t) << 6;                                                     \
    _Pragma("unroll") for (int j_ = 0; j_ < 2; ++j_) {                            \
      const int row_ = (h) * 128 + j_ * 64 + wid * 8;                             \
      const short* g_ = A + (size_t)(m0 + row_ + srl) * K + kt_ + sch;            \
      __builtin_amdgcn_global_load_lds(GLB_CAST(g_), LDS_CAST(&as[(b)][row_ * 64]), 16, 0, 0); \
    }                                                                             \
  } while (0)

#define STAGE_B(t, h, b)                                                          \
  do {                                                                            \
    const int kt_ = (t) << 6;                                                     \
    _Pragma("unroll") for (int j_ = 0; j_ < 2; ++j_) {                            \
      const int row_ = (h) * 128 + j_ * 64 + wid * 8;                             \
      const short* g_ = Bt + (size_t)(n0 + row_ + srl) * K + kt_ + sch;           \
      __builtin_amdgcn_global_load_lds(GLB_CAST(g_), LDS_CAST(&bs[(b)][row_ * 64]), 16, 0, 0); \
    }                                                                             \
  } while (0)

#define SLOT_(kc) ((((kc) * 4 + quad) ^ (l16 & 7)) * 8)

#define LOAD_A(dst, mh, b)                                                        \
  do {                                                                            \
    _Pragma("unroll") for (int mf_ = 0; mf_ < 4; ++mf_)                           \
    _Pragma("unroll") for (int kc_ = 0; kc_ < 2; ++kc_)                           \
      dst[mf_][kc_] = *(const short8*)&as[(b)][(wm * 128 + (mh) * 64 + mf_ * 16 + l16) * 64 + SLOT_(kc_)]; \
  } while (0)

#define LOAD_B(dst, nh, b)                                                        \
  do {                                                                            \
    _Pragma("unroll") for (int nf_ = 0; nf_ < 2; ++nf_)                           \
    _Pragma("unroll") for (int kc_ = 0; kc_ < 2; ++kc_)                           \
      dst[nf_][kc_] = *(const short8*)&bs[(b)][(wn * 64 + (nh) * 32 + nf_ * 16 + l16) * 64 + SLOT_(kc_)]; \
  } while (0)

#define QMFMA(afrag, bfrag, mh, nh)                                               \
  do {                                                                            \
    __builtin_amdgcn_s_setprio(1);                                                \
    _Pragma("unroll") for (int mf_ = 0; mf_ < 4; ++mf_)                           \
    _Pragma("unroll") for (int nf_ = 0; nf_ < 2; ++nf_)                           \
    _Pragma("unroll") for (int kc_ = 0; kc_ < 2; ++kc_)                           \
      acc[(mh) * 4 + mf_][(nh) * 2 + nf_] =                                       \
          mfma_bf16(afrag[mf_][kc_], bfrag[nf_][kc_], acc[(mh) * 4 + mf_][(nh) * 2 + nf_]); \
    __builtin_amdgcn_s_setprio(0);                                                \
  } while (0)

  // pre-MFMA sync: barrier, then lgkm drain (doubles as code-motion fence)
#define BARW_()                                                                   \
  do {                                                                            \
    __builtin_amdgcn_s_barrier();                                                 \
    asm volatile("s_waitcnt lgkmcnt(0)" ::: "memory");                            \
  } while (0)

  const floatx4 zero4 = {0.f, 0.f, 0.f, 0.f};
  floatx4 acc[8][4];
#pragma unroll
  for (int i = 0; i < 8; ++i)
#pragma unroll
    for (int j = 0; j < 4; ++j) acc[i][j] = zero4;

  // ---- prologue: issue order must match steady-state so vmcnt counts work
  STAGE_B(0, 0, 0); STAGE_B(0, 1, 0);
  STAGE_A(0, 0, 0); STAGE_A(0, 1, 0);
  STAGE_B(1, 0, 1); STAGE_B(1, 1, 1);
  asm volatile("s_waitcnt vmcnt(4)" ::: "memory");  // tile0 landed; B(1) floats
  __builtin_amdgcn_s_barrier();

  short8 afr[4][2], bf0[2][2], bf1[2][2];

  for (int t = 0; t < NT; ++t) {
    const int cb = t & 1, nb = cb ^ 1;
    const int tA = (t + 1 < NT) ? t + 1 : NT - 1;  // clamped tail keeps vmcnt
    const int tB = (t + 2 < NT) ? t + 2 : NT - 1;  // counts uniform (junk-safe)

    // ---- phase 0: quadrant (mh0,nh0)
    LOAD_A(afr, 0, cb);
    LOAD_B(bf0, 0, cb);   // kept in regs through phase 3
    STAGE_A(tA, 0, nb);
    BARW_();
    QMFMA(afr, bf0, 0, 0);
    __builtin_amdgcn_s_barrier();

    // ---- phase 1: quadrant (mh0,nh1)
    LOAD_B(bf1, 1, cb);
    STAGE_A(tA, 1, nb);
    BARW_();
    QMFMA(afr, bf1, 0, 1);
    __builtin_amdgcn_s_barrier();

    // ---- phase 2: quadrant (mh1,nh1)
    LOAD_A(afr, 1, cb);
    STAGE_B(tB, 0, cb);   // cb's B fully read by end of phase 1
    BARW_();
    QMFMA(afr, bf1, 1, 1);
    __builtin_amdgcn_s_barrier();

    // ---- phase 3: quadrant (mh1,nh0) -- no ds_read, uses kept bf0
    STAGE_B(tB, 1, cb);
    asm volatile("s_waitcnt vmcnt(4)" ::: "memory");  // next tile confirmed
    BARW_();
    QMFMA(afr, bf0, 1, 0);
    __builtin_amdgcn_s_barrier();
  }
  // drain tail junk-stage DMAs before LDS can be handed to the next block
  asm volatile("s_waitcnt vmcnt(0)" ::: "memory");

  // ---- epilogue
  const int row0 = m0 + wm * 128 + quad * 4;
  const int col0 = n0 + wn * 64 + l16;
  if (mode == 2 && n0 >= 2048) {
    // V part -> transposed vT[(b*16+h)*64+d][t]
#pragma unroll
    for (int mi = 0; mi < 8; ++mi)
#pragma unroll
      for (int ni = 0; ni < 4; ++ni)
#pragma unroll
        for (int r = 0; r < 4; ++r) {
          const int row = row0 + mi * 16 + r;
          const int col = col0 + ni * 16;
          const int d = col & 63, hh = (col >> 6) - 32;
          const int bb = row >> 11, tq = row & 2047;
          C2[((size_t)(bb * 16 + hh) * 64 + d) * T_SEQ + tq] = f2bf(acc[mi][ni][r]);
        }
  } else {
    const int outN = (mode == 2) ? 2048 : N;
#pragma unroll
    for (int mi = 0; mi < 8; ++mi)
#pragma unroll
      for (int ni = 0; ni < 4; ++ni)
#pragma unroll
        for (int r = 0; r < 4; ++r) {
          const size_t off = (size_t)(row0 + mi * 16 + r) * outN + col0 + ni * 16;
          if (out_f32) ((float*)C)[off] = acc[mi][ni][r];
          else         ((short*)C)[off] = f2bf(acc[mi][ni][r]);
        }
  }
#undef STAGE_A
#undef STAGE_B
#undef SLOT_
#undef LOAD_A
#undef LOAD_B
#undef QMFMA
#undef BARW_
}

// ---- flash attention (round-6 validated version, unchanged) ---------------
// qk [b*2048+t][2048] (Q cols 0..1023, K cols 1024..2047), vT [(b*16+h)*64+d][t].
// Block = 4 waves x 16 queries; BK=64. K/V tiles shared by all 4 waves.
__global__ __launch_bounds__(256) void attn(const short* __restrict__ qk,
                                            const short* __restrict__ vT,
                                            short* __restrict__ y) {
  __shared__ short ks[64 * 64];    // [key][d], 8 chunks/row XOR-swizzled
  __shared__ short vs[64 * 64];    // [d][key], same swizzle
  __shared__ short ps[4][16][72];  // per-wave P [q][key]
  const int tid = threadIdx.x;
  const int wid = tid >> 6, lane = tid & 63;
  const int quad = lane >> 4, l16 = lane & 15;
  const int b = blockIdx.x >> 4, h = blockIdx.x & 15;
  const int q0 = ((int)gridDim.y - 1 - (int)blockIdx.y) * 64;  // heavy blocks first
  const int qw0 = q0 + wid * 16;

  const short* qbase = qk + (size_t)b * T_SEQ * 2048 + h * DHEAD;
  const short* kbase = qbase + DMODEL;
  const short* vtb = vT + (size_t)(b * NHEADS + h) * DHEAD * T_SEQ;
  const float SC = 0.18033688011112042f;  // 0.125 * log2(e), folded into Q

  // Q fragments (A-layout m=l16, k=quad*8+j), pre-scaled by SC
  short8 aq[2];
#pragma unroll
  for (int kc = 0; kc < 2; ++kc) {
    short8 raw = *(const short8*)(qbase + (size_t)(qw0 + l16) * 2048 + kc * 32 + quad * 8);
#pragma unroll
    for (int j = 0; j < 8; ++j) aq[kc][j] = f2bf(bf2f(raw[j]) * SC);
  }

  const floatx4 zero4 = {0.f, 0.f, 0.f, 0.f};
  floatx4 o[4], lacc = zero4;  // lacc: row-sum via ones-MFMA
#pragma unroll
  for (int i = 0; i < 4; ++i) o[i] = zero4;
  const short8 ones8 = {0x3F80, 0x3F80, 0x3F80, 0x3F80, 0x3F80, 0x3F80, 0x3F80, 0x3F80};

  // staging lane map: row = i*32 + wid*8 + (lane>>3), chunk = (lane&7) ^ (row&7)
  const int srl = lane >> 3;
  const int sch = ((lane & 7) ^ srl) * 8;

  const int kend = q0 + 64;
  for (int kt = 0; kt < kend; kt += 64) {
    __syncthreads();  // prev iteration's LDS readers done
#pragma unroll
    for (int i = 0; i < 2; ++i) {
      const int row = i * 32 + wid * 8 + srl;
      const short* gk = kbase + (size_t)(kt + row) * 2048 + sch;
      const short* gv = vtb + (size_t)row * T_SEQ + kt + sch;
      __builtin_amdgcn_global_load_lds(GLB_CAST(gk), LDS_CAST(ks + (i * 32 + wid * 8) * 64), 16, 0, 0);
      __builtin_amdgcn_global_load_lds(GLB_CAST(gv), LDS_CAST(vs + (i * 32 + wid * 8) * 64), 16, 0, 0);
    }
    __syncthreads();  // DMA drained

    // S = Q K^T : 16q x 64key per wave; B-frag chunk kc*4+quad at swizzled slot
    floatx4 s[4];
#pragma unroll
    for (int nt = 0; nt < 4; ++nt) {
      s[nt] = zero4;
#pragma unroll
      for (int kc = 0; kc < 2; ++kc) {
        const int slot = ((kc * 4 + quad) ^ (l16 & 7)) * 8;
        const short8 bk = *(const short8*)&ks[(nt * 16 + l16) * 64 + slot];
        s[nt] = mfma_bf16(aq[kc], bk, s[nt]);
      }
    }

    // max-free softmax: p = 2^s; zero masked keys (diagonal tiles only)
    const bool full = (kt + 63 <= qw0);  // wave-uniform
#pragma unroll
    for (int nt = 0; nt < 4; ++nt)
#pragma unroll
      for (int r = 0; r < 4; ++r) {
        float p = exp2_(s[nt][r]);
        if (!full) {
          const int key = kt + nt * 16 + l16;
          const int q = qw0 + quad * 4 + r;
          p = (key <= q) ? p : 0.f;
        }
        s[nt][r] = p;
      }

    // P (C-layout) -> per-wave LDS [q][key] (wave-internal, no barrier)
#pragma unroll
    for (int nt = 0; nt < 4; ++nt)
#pragma unroll
      for (int r = 0; r < 4; ++r)
        ps[wid][quad * 4 + r][nt * 16 + l16] = f2bf(s[nt][r]);

    // O += P V ; l += P 1
#pragma unroll
    for (int kc = 0; kc < 2; ++kc) {
      const short8 ap = *(const short8*)&ps[wid][l16][kc * 32 + quad * 8];
      lacc = mfma_bf16(ap, ones8, lacc);
#pragma unroll
      for (int d4 = 0; d4 < 4; ++d4) {
        const int slot = ((kc * 4 + quad) ^ (l16 & 7)) * 8;
        const short8 bv = *(const short8*)&vs[(d4 * 16 + l16) * 64 + slot];
        o[d4] = mfma_bf16(ap, bv, o[d4]);
      }
    }
  }

  // epilogue: O /= l
  floatx4 inv;
#pragma unroll
  for (int r = 0; r < 4; ++r) inv[r] = 1.0f / lacc[r];
#pragma unroll
  for (int d4 = 0; d4 < 4; ++d4)
#pragma unroll
    for (int r = 0; r < 4; ++r) {
      const int q = qw0 + quad * 4 + r;
      y[(size_t)(b * T_SEQ + q) * DMODEL + h * DHEAD + d4 * 16 + l16] =
          f2bf(o[d4][r] * inv[r]);
    }
}

extern "C" void kernel_launch(void* const* d_in, const int* in_sizes, int n_in,
                              void* d_out, int out_size, void* d_ws, size_t ws_size,
                              hipStream_t stream) {
  const char* x = (const char*)d_in[0];       // [4,2048,1024] fp32 (or bf16)
  const char* w_qkv = (const char*)d_in[1];   // [1024,3072]
  const char* w_proj = (const char*)d_in[2];  // [1024,1024]
  const unsigned* xs = (const unsigned*)d_in[0];

  // ws: qk(33.6M) | vT(16.8M) | wqkvT(6.3M) | wprojT(2.1M) | xbf=ybuf(16.8M) = 75.5MB
  short* qk = (short*)d_ws;                          // 8192*2048
  short* vTb = qk + (size_t)8192 * 2048;             // 64*64*2048
  short* wqkvT = vTb + (size_t)64 * 64 * 2048;       // 3072*1024
  short* wprojT = wqkvT + (size_t)3072 * 1024;       // 1024*1024
  short* xbf = wprojT + (size_t)1024 * 1024;         // 8192*1024
  short* ybuf = xbf;                                 // alias: xbf dead after gemm1

  conv_x<<<8192 * 1024 / (256 * 8), 256, 0, stream>>>(x, xbf, 8192 * 1024, xs);
  {
    dim3 g1(3072 / 32, 1024 / 32);
    tpose<<<g1, 256, 0, stream>>>(w_qkv, wqkvT, 1024, 3072, xs);
    dim3 g2(1024 / 32, 1024 / 32);
    tpose<<<g2, 256, 0, stream>>>(w_proj, wprojT, 1024, 1024, xs);
  }
  {  // qkv projection with split epilogue: Q,K -> qk ; V -> vT (transposed)
    dim3 grid(3072 / 256, 8192 / 256);  // 12 x 32 = 384 blocks (384 % 8 == 0)
    gemm256<<<grid, 512, 0, stream>>>(xbf, wqkvT, qk, vTb, 8192, 3072, 1024, 2, xs);
  }
  {
    dim3 grid(4 * NHEADS, T_SEQ / 64);
    attn<<<grid, 256, 0, stream>>>(qk, vTb, ybuf);
  }
  {
    dim3 grid(1024 / 256, 8192 / 256);  // 4 x 32 = 128 blocks (128 % 8 == 0)
    gemm256<<<grid, 512, 0, stream>>>(ybuf, wprojT, d_out, nullptr, 8192, 1024, 1024, 1, xs);
  }
}

// Round 4
// 273.401 us; speedup vs baseline: 1.0385x; 1.0346x over previous
//
#include <hip/hip_runtime.h>
#include <hip/hip_bf16.h>
#include <cmath>

#define T_SEQ 2048
#define NHEADS 16
#define DHEAD 64
#define DMODEL 1024
#define CQKV 3072

typedef __attribute__((ext_vector_type(8))) short short8;
typedef __attribute__((ext_vector_type(8))) __bf16 bf16x8;
typedef __attribute__((ext_vector_type(4))) float floatx4;

#define LDS_CAST(p) ((__attribute__((address_space(3))) void*)(p))
#define GLB_CAST(p) ((const __attribute__((address_space(1))) void*)(p))

static __device__ __forceinline__ floatx4 mfma_bf16(short8 a, short8 b, floatx4 c) {
  return __builtin_amdgcn_mfma_f32_16x16x32_bf16(
      __builtin_bit_cast(bf16x8, a), __builtin_bit_cast(bf16x8, b), c, 0, 0, 0);
}

// fp32 -> bf16 round-to-nearest-even, bit carrier = short
static __device__ __forceinline__ short f2bf(float f) {
  union { float f; unsigned u; } x; x.f = f;
  unsigned r = x.u + 0x7FFFu + ((x.u >> 16) & 1u);
  return (short)(r >> 16);
}

static __device__ __forceinline__ float bf2f(short s) {
  return __builtin_bit_cast(float, ((unsigned)(unsigned short)s) << 16);
}

static __device__ __forceinline__ float exp2_(float x) {
#if __has_builtin(__builtin_amdgcn_exp2f)
  return __builtin_amdgcn_exp2f(x);
#else
  return exp2f(x);
#endif
}

// bf16 vs fp32 input sniff (round-1 notes). 16-of-32 exponent vote.
static __device__ __forceinline__ bool sniff_is_bf16(const unsigned* __restrict__ x) {
  int cnt = 0;
#pragma unroll
  for (int i = 0; i < 32; ++i) {
    unsigned e = (x[i] >> 7) & 0xFFu;
    cnt += (e >= 0x70u && e <= 0x8Fu) ? 1 : 0;
  }
  return cnt >= 16;
}

static __device__ __forceinline__ short8 load8f32(const char* p, size_t idx) {
  const float4* f = (const float4*)(p + idx * 4);
  float4 a = f[0], b = f[1];
  short8 r;
  r[0] = f2bf(a.x); r[1] = f2bf(a.y); r[2] = f2bf(a.z); r[3] = f2bf(a.w);
  r[4] = f2bf(b.x); r[5] = f2bf(b.y); r[6] = f2bf(b.z); r[7] = f2bf(b.w);
  return r;
}

// ---- preprocessing: x -> bf16 copy/convert --------------------------------
__global__ __launch_bounds__(256) void conv_x(const char* __restrict__ x,
                                              short* __restrict__ o, int n,
                                              const unsigned* __restrict__ xs) {
  const bool isbf = sniff_is_bf16(xs);
  const int i = (blockIdx.x * 256 + threadIdx.x) * 8;
  if (i >= n) return;
  if (isbf) *(short8*)(o + i) = *(const short8*)((const short*)x + i);
  else      *(short8*)(o + i) = load8f32(x, (size_t)i);
}

// ---- preprocessing: W [K][N] -> W^T [N][K] bf16 ---------------------------
__global__ __launch_bounds__(256) void tpose(const char* __restrict__ w,
                                             short* __restrict__ wt, int K, int N,
                                             const unsigned* __restrict__ xs) {
  const bool isbf = sniff_is_bf16(xs);
  __shared__ short tile[32][33];
  const int n0 = blockIdx.x * 32, k0 = blockIdx.y * 32;
  const int tx = threadIdx.x & 31, ty = threadIdx.x >> 5;  // 32 x 8
#pragma unroll
  for (int i = 0; i < 4; ++i) {
    const int r = ty * 4 + i;
    const size_t off = (size_t)(k0 + r) * N + n0 + tx;
    tile[r][tx] = isbf ? ((const short*)w)[off] : f2bf(((const float*)w)[off]);
  }
  __syncthreads();
#pragma unroll
  for (int i = 0; i < 4; ++i) {
    const int r = ty * 4 + i;
    wt[(size_t)(n0 + r) * K + k0 + tx] = tile[tx][r];
  }
}

// ---- GEMM (256x256, 8-phase counted-vmcnt, m201 template) -----------------
// Used ONLY where the grid is large enough (QKV: 384 blocks). Round-3
// measured: 87 us, MfmaUtil 24%, bank-conflict 0.
// mode 2: QKV split: cols [0,2048) -> qk [M,2048]; cols [2048,3072) -> vT.
__global__ __launch_bounds__(512) void gemm256(const short* __restrict__ A,
                                               const short* __restrict__ Bt,
                                               void* __restrict__ C,
                                               short* __restrict__ C2,
                                               int M, int N, int K, int mode,
                                               const unsigned* __restrict__ xs) {
  const bool out_f32 = (mode == 1) ? !sniff_is_bf16(xs) : false;

  __shared__ short as[2][256 * 64];  // 64 KiB
  __shared__ short bs[2][256 * 64];  // 64 KiB
  const int tid = threadIdx.x;
  const int wid = tid >> 6, lane = tid & 63;
  const int quad = lane >> 4, l16 = lane & 15;
  const int wm = wid >> 2, wn = wid & 3;  // 2 x 4 wave grid, each owns 128x64

  // XCD-aware bijective blockIdx swizzle (grids are multiples of 8)
  const int gx = (int)gridDim.x;
  const int nwg = gx * (int)gridDim.y;
  int bid = (int)blockIdx.y * gx + (int)blockIdx.x;
  bid = (bid & 7) * (nwg >> 3) + (bid >> 3);
  const int m0 = (bid / gx) * 256;
  const int n0 = (bid % gx) * 256;

  const int srl = lane >> 3;               // staging: row within 8-row group
  const int sch = ((lane & 7) ^ srl) * 8;  // XOR-swizzled source chunk (shorts)
  const int NT = K >> 6;

#define STAGE_A(t, h, b)                                                          \
  do {                                                                            \
    const int kt_ = (t) << 6;                                                     \
    _Pragma("unroll") for (int j_ = 0; j_ < 2; ++j_) {                            \
      const int row_ = (h) * 128 + j_ * 64 + wid * 8;                             \
      const short* g_ = A + (size_t)(m0 + row_ + srl) * K + kt_ + sch;            \
      __builtin_amdgcn_global_load_lds(GLB_CAST(g_), LDS_CAST(&as[(b)][row_ * 64]), 16, 0, 0); \
    }                                                                             \
  } while (0)

#define STAGE_B(t, h, b)                                                          \
  do {                                                                            \
    const int kt_ = (t) << 6;                                                     \
    _Pragma("unroll") for (int j_ = 0; j_ < 2; ++j_) {                            \
      const int row_ = (h) * 128 + j_ * 64 + wid * 8;                             \
      const short* g_ = Bt + (size_t)(n0 + row_ + srl) * K + kt_ + sch;           \
      __builtin_amdgcn_global_load_lds(GLB_CAST(g_), LDS_CAST(&bs[(b)][row_ * 64]), 16, 0, 0); \
    }                                                                             \
  } while (0)

#define SLOT_(kc) ((((kc) * 4 + quad) ^ (l16 & 7)) * 8)

#define LOAD_A(dst, mh, b)                                                        \
  do {                                                                            \
    _Pragma("unroll") for (int mf_ = 0; mf_ < 4; ++mf_)                           \
    _Pragma("unroll") for (int kc_ = 0; kc_ < 2; ++kc_)                           \
      dst[mf_][kc_] = *(const short8*)&as[(b)][(wm * 128 + (mh) * 64 + mf_ * 16 + l16) * 64 + SLOT_(kc_)]; \
  } while (0)

#define LOAD_B(dst, nh, b)                                                        \
  do {                                                                            \
    _Pragma("unroll") for (int nf_ = 0; nf_ < 2; ++nf_)                           \
    _Pragma("unroll") for (int kc_ = 0; kc_ < 2; ++kc_)                           \
      dst[nf_][kc_] = *(const short8*)&bs[(b)][(wn * 64 + (nh) * 32 + nf_ * 16 + l16) * 64 + SLOT_(kc_)]; \
  } while (0)

#define QMFMA(afrag, bfrag, mh, nh)                                               \
  do {                                                                            \
    __builtin_amdgcn_s_setprio(1);                                                \
    _Pragma("unroll") for (int mf_ = 0; mf_ < 4; ++mf_)                           \
    _Pragma("unroll") for (int nf_ = 0; nf_ < 2; ++nf_)                           \
    _Pragma("unroll") for (int kc_ = 0; kc_ < 2; ++kc_)                           \
      acc[(mh) * 4 + mf_][(nh) * 2 + nf_] =                                       \
          mfma_bf16(afrag[mf_][kc_], bfrag[nf_][kc_], acc[(mh) * 4 + mf_][(nh) * 2 + nf_]); \
    __builtin_amdgcn_s_setprio(0);                                                \
  } while (0)

  // pre-MFMA sync: barrier, then lgkm drain (doubles as code-motion fence)
#define BARW_()                                                                   \
  do {                                                                            \
    __builtin_amdgcn_s_barrier();                                                 \
    asm volatile("s_waitcnt lgkmcnt(0)" ::: "memory");                            \
  } while (0)

  const floatx4 zero4 = {0.f, 0.f, 0.f, 0.f};
  floatx4 acc[8][4];
#pragma unroll
  for (int i = 0; i < 8; ++i)
#pragma unroll
    for (int j = 0; j < 4; ++j) acc[i][j] = zero4;

  // ---- prologue: issue order must match steady-state so vmcnt counts work
  STAGE_B(0, 0, 0); STAGE_B(0, 1, 0);
  STAGE_A(0, 0, 0); STAGE_A(0, 1, 0);
  STAGE_B(1, 0, 1); STAGE_B(1, 1, 1);
  asm volatile("s_waitcnt vmcnt(4)" ::: "memory");  // tile0 landed; B(1) floats
  __builtin_amdgcn_s_barrier();

  short8 afr[4][2], bf0[2][2], bf1[2][2];

  for (int t = 0; t < NT; ++t) {
    const int cb = t & 1, nb = cb ^ 1;
    const int tA = (t + 1 < NT) ? t + 1 : NT - 1;  // clamped tail keeps vmcnt
    const int tB = (t + 2 < NT) ? t + 2 : NT - 1;  // counts uniform (junk-safe)

    // ---- phase 0: quadrant (mh0,nh0)
    LOAD_A(afr, 0, cb);
    LOAD_B(bf0, 0, cb);   // kept in regs through phase 3
    STAGE_A(tA, 0, nb);
    BARW_();
    QMFMA(afr, bf0, 0, 0);
    __builtin_amdgcn_s_barrier();

    // ---- phase 1: quadrant (mh0,nh1)
    LOAD_B(bf1, 1, cb);
    STAGE_A(tA, 1, nb);
    BARW_();
    QMFMA(afr, bf1, 0, 1);
    __builtin_amdgcn_s_barrier();

    // ---- phase 2: quadrant (mh1,nh1)
    LOAD_A(afr, 1, cb);
    STAGE_B(tB, 0, cb);   // cb's B fully read by end of phase 1
    BARW_();
    QMFMA(afr, bf1, 1, 1);
    __builtin_amdgcn_s_barrier();

    // ---- phase 3: quadrant (mh1,nh0) -- no ds_read, uses kept bf0
    STAGE_B(tB, 1, cb);
    asm volatile("s_waitcnt vmcnt(4)" ::: "memory");  // next tile confirmed
    BARW_();
    QMFMA(afr, bf0, 1, 0);
    __builtin_amdgcn_s_barrier();
  }
  // drain tail junk-stage DMAs before LDS can be handed to the next block
  asm volatile("s_waitcnt vmcnt(0)" ::: "memory");

  // ---- epilogue
  const int row0 = m0 + wm * 128 + quad * 4;
  const int col0 = n0 + wn * 64 + l16;
  if (mode == 2 && n0 >= 2048) {
    // V part -> transposed vT[(b*16+h)*64+d][t]
#pragma unroll
    for (int mi = 0; mi < 8; ++mi)
#pragma unroll
      for (int ni = 0; ni < 4; ++ni)
#pragma unroll
        for (int r = 0; r < 4; ++r) {
          const int row = row0 + mi * 16 + r;
          const int col = col0 + ni * 16;
          const int d = col & 63, hh = (col >> 6) - 32;
          const int bb = row >> 11, tq = row & 2047;
          C2[((size_t)(bb * 16 + hh) * 64 + d) * T_SEQ + tq] = f2bf(acc[mi][ni][r]);
        }
  } else {
    const int outN = (mode == 2) ? 2048 : N;
#pragma unroll
    for (int mi = 0; mi < 8; ++mi)
#pragma unroll
      for (int ni = 0; ni < 4; ++ni)
#pragma unroll
        for (int r = 0; r < 4; ++r) {
          const size_t off = (size_t)(row0 + mi * 16 + r) * outN + col0 + ni * 16;
          if (out_f32) ((float*)C)[off] = acc[mi][ni][r];
          else         ((short*)C)[off] = f2bf(acc[mi][ni][r]);
        }
  }
#undef STAGE_A
#undef STAGE_B
#undef SLOT_
#undef LOAD_A
#undef LOAD_B
#undef QMFMA
#undef BARW_
}

// ---- GEMM: 128x128 tile (round-0 verbatim) -- for small-grid GEMMs --------
// proj (N=1024) only gets 128 blocks at 256^2; at 128^2 it gets 512 blocks
// and measured ~33 us in the round-0 composition. 32 KiB LDS -> multi-block/CU.
__global__ __launch_bounds__(256) void gemm128(const short* __restrict__ A,
                                               const short* __restrict__ Bt,
                                               void* __restrict__ C,
                                               short* __restrict__ C2,
                                               int M, int N, int K, int mode,
                                               const unsigned* __restrict__ xs) {
  const bool out_f32 = (mode == 1) ? !sniff_is_bf16(xs) : false;

  __shared__ short as[128 * 64];
  __shared__ short bs[128 * 64];
  const int tid = threadIdx.x;
  const int wid = tid >> 6, lane = tid & 63;
  const int quad = lane >> 4, l16 = lane & 15;
  const int wm = wid >> 1, wn = wid & 1;
  const int m0 = blockIdx.y * 128, n0 = blockIdx.x * 128;

  const int srl = lane >> 3;               // row within the 8-row group
  const int sch = ((lane & 7) ^ srl) * 8;  // XOR-swizzled 16B chunk (shorts)

  const floatx4 zero4 = {0.f, 0.f, 0.f, 0.f};
  floatx4 acc[4][4];
#pragma unroll
  for (int i = 0; i < 4; ++i)
#pragma unroll
    for (int j = 0; j < 4; ++j) acc[i][j] = zero4;

  for (int kt = 0; kt < K; kt += 64) {
    __syncthreads();
#pragma unroll
    for (int i = 0; i < 4; ++i) {
      const int row = wid * 32 + i * 8;
      const short* ga = A + (size_t)(m0 + row + srl) * K + kt + sch;
      const short* gb = Bt + (size_t)(n0 + row + srl) * K + kt + sch;
      __builtin_amdgcn_global_load_lds(GLB_CAST(ga), LDS_CAST(as + row * 64), 16, 0, 0);
      __builtin_amdgcn_global_load_lds(GLB_CAST(gb), LDS_CAST(bs + row * 64), 16, 0, 0);
    }
    __syncthreads();

#pragma unroll
    for (int kc = 0; kc < 2; ++kc) {
      const int slot = ((kc * 4 + quad) ^ (l16 & 7)) * 8;
      short8 afr[4], bfr[4];
#pragma unroll
      for (int mt = 0; mt < 4; ++mt)
        afr[mt] = *(const short8*)&as[(wm * 64 + mt * 16 + l16) * 64 + slot];
#pragma unroll
      for (int nt = 0; nt < 4; ++nt)
        bfr[nt] = *(const short8*)&bs[(wn * 64 + nt * 16 + l16) * 64 + slot];
#pragma unroll
      for (int mt = 0; mt < 4; ++mt)
#pragma unroll
        for (int nt = 0; nt < 4; ++nt)
          acc[mt][nt] = mfma_bf16(afr[mt], bfr[nt], acc[mt][nt]);
    }
  }

  const int row0 = m0 + wm * 64 + quad * 4;
  const int col0 = n0 + wn * 64 + l16;
  if (mode == 2 && n0 >= 2048) {
#pragma unroll
    for (int mt = 0; mt < 4; ++mt)
#pragma unroll
      for (int nt = 0; nt < 4; ++nt)
#pragma unroll
        for (int r = 0; r < 4; ++r) {
          const int row = row0 + mt * 16 + r;
          const int col = col0 + nt * 16;
          const int d = col & 63, hh = (col >> 6) - 32;
          const int bb = row >> 11, t = row & 2047;
          C2[((size_t)(bb * 16 + hh) * 64 + d) * T_SEQ + t] = f2bf(acc[mt][nt][r]);
        }
  } else {
    const int outN = (mode == 2) ? 2048 : N;
#pragma unroll
    for (int mt = 0; mt < 4; ++mt)
#pragma unroll
      for (int nt = 0; nt < 4; ++nt)
#pragma unroll
        for (int r = 0; r < 4; ++r) {
          const size_t off = (size_t)(row0 + mt * 16 + r) * outN + col0 + nt * 16;
          if (out_f32) ((float*)C)[off] = acc[mt][nt][r];
          else         ((short*)C)[off] = f2bf(acc[mt][nt][r]);
        }
  }
}

// ---- flash attention, now with K/V LDS double-buffer ----------------------
// qk [b*2048+t][2048] (Q cols 0..1023, K cols 1024..2047), vT [(b*16+h)*64+d][t].
// Block = 4 waves x 16 queries; BK=64. K/V tiles shared by all 4 waves.
// dbuf: stage tile t+1 right after the single per-tile __syncthreads; the
// NEXT iteration's __syncthreads (implicit vmcnt(0) drain) completes it, so
// DMA latency hides under tile-t compute and barrier count halves.
__global__ __launch_bounds__(256) void attn(const short* __restrict__ qk,
                                            const short* __restrict__ vT,
                                            short* __restrict__ y) {
  __shared__ short ks[2][64 * 64];  // [key][d], 8 chunks/row XOR-swizzled
  __shared__ short vs[2][64 * 64];  // [d][key], same swizzle
  __shared__ short ps[4][16][72];   // per-wave P [q][key]
  const int tid = threadIdx.x;
  const int wid = tid >> 6, lane = tid & 63;
  const int quad = lane >> 4, l16 = lane & 15;
  const int b = blockIdx.x >> 4, h = blockIdx.x & 15;
  const int q0 = ((int)gridDim.y - 1 - (int)blockIdx.y) * 64;  // heavy blocks first
  const int qw0 = q0 + wid * 16;

  const short* qbase = qk + (size_t)b * T_SEQ * 2048 + h * DHEAD;
  const short* kbase = qbase + DMODEL;
  const short* vtb = vT + (size_t)(b * NHEADS + h) * DHEAD * T_SEQ;
  const float SC = 0.18033688011112042f;  // 0.125 * log2(e), folded into Q

  // staging lane map: row = i*32 + wid*8 + (lane>>3), chunk = (lane&7) ^ (row&7)
  const int srl = lane >> 3;
  const int sch = ((lane & 7) ^ srl) * 8;

  // Q fragments (A-layout m=l16, k=quad*8+j), pre-scaled by SC
  short8 aq[2];
#pragma unroll
  for (int kc = 0; kc < 2; ++kc) {
    short8 raw = *(const short8*)(qbase + (size_t)(qw0 + l16) * 2048 + kc * 32 + quad * 8);
#pragma unroll
    for (int j = 0; j < 8; ++j) aq[kc][j] = f2bf(bf2f(raw[j]) * SC);
  }

  const floatx4 zero4 = {0.f, 0.f, 0.f, 0.f};
  floatx4 o[4], lacc = zero4;  // lacc: row-sum via ones-MFMA
#pragma unroll
  for (int i = 0; i < 4; ++i) o[i] = zero4;
  const short8 ones8 = {0x3F80, 0x3F80, 0x3F80, 0x3F80, 0x3F80, 0x3F80, 0x3F80, 0x3F80};

  const int kend = q0 + 64;

  // prologue: stage tile 0 into buffer 0
#pragma unroll
  for (int i = 0; i < 2; ++i) {
    const int row = i * 32 + wid * 8 + srl;
    const short* gk = kbase + (size_t)row * 2048 + sch;
    const short* gv = vtb + (size_t)row * T_SEQ + sch;
    __builtin_amdgcn_global_load_lds(GLB_CAST(gk), LDS_CAST(&ks[0][(i * 32 + wid * 8) * 64]), 16, 0, 0);
    __builtin_amdgcn_global_load_lds(GLB_CAST(gv), LDS_CAST(&vs[0][(i * 32 + wid * 8) * 64]), 16, 0, 0);
  }

  int cur = 0;
  for (int kt = 0; kt < kend; kt += 64, cur ^= 1) {
    __syncthreads();  // drains tile-kt DMA (vmcnt 0) + all prev-buf readers done

    if (kt + 64 < kend) {  // stage next tile into the other buffer
      const int nxt = cur ^ 1;
#pragma unroll
      for (int i = 0; i < 2; ++i) {
        const int row = i * 32 + wid * 8 + srl;
        const short* gk = kbase + (size_t)(kt + 64 + row) * 2048 + sch;
        const short* gv = vtb + (size_t)row * T_SEQ + kt + 64 + sch;
        __builtin_amdgcn_global_load_lds(GLB_CAST(gk), LDS_CAST(&ks[nxt][(i * 32 + wid * 8) * 64]), 16, 0, 0);
        __builtin_amdgcn_global_load_lds(GLB_CAST(gv), LDS_CAST(&vs[nxt][(i * 32 + wid * 8) * 64]), 16, 0, 0);
      }
    }

    const short* ksc = &ks[cur][0];
    const short* vsc = &vs[cur][0];

    // S = Q K^T : 16q x 64key per wave; B-frag chunk kc*4+quad at swizzled slot
    floatx4 s[4];
#pragma unroll
    for (int nt = 0; nt < 4; ++nt) {
      s[nt] = zero4;
#pragma unroll
      for (int kc = 0; kc < 2; ++kc) {
        const int slot = ((kc * 4 + quad) ^ (l16 & 7)) * 8;
        const short8 bk = *(const short8*)&ksc[(nt * 16 + l16) * 64 + slot];
        s[nt] = mfma_bf16(aq[kc], bk, s[nt]);
      }
    }

    // max-free softmax: p = 2^s; zero masked keys (diagonal tiles only)
    const bool full = (kt + 63 <= qw0);  // wave-uniform
#pragma unroll
    for (int nt = 0; nt < 4; ++nt)
#pragma unroll
      for (int r = 0; r < 4; ++r) {
        float p = exp2_(s[nt][r]);
        if (!full) {
          const int key = kt + nt * 16 + l16;
          const int q = qw0 + quad * 4 + r;
          p = (key <= q) ? p : 0.f;
        }
        s[nt][r] = p;
      }

    // P (C-layout) -> per-wave LDS [q][key] (wave-internal, no barrier)
#pragma unroll
    for (int nt = 0; nt < 4; ++nt)
#pragma unroll
      for (int r = 0; r < 4; ++r)
        ps[wid][quad * 4 + r][nt * 16 + l16] = f2bf(s[nt][r]);

    // O += P V ; l += P 1
#pragma unroll
    for (int kc = 0; kc < 2; ++kc) {
      const short8 ap = *(const short8*)&ps[wid][l16][kc * 32 + quad * 8];
      lacc = mfma_bf16(ap, ones8, lacc);
#pragma unroll
      for (int d4 = 0; d4 < 4; ++d4) {
        const int slot = ((kc * 4 + quad) ^ (l16 & 7)) * 8;
        const short8 bv = *(const short8*)&vsc[(d4 * 16 + l16) * 64 + slot];
        o[d4] = mfma_bf16(ap, bv, o[d4]);
      }
    }
  }

  // epilogue: O /= l
  floatx4 inv;
#pragma unroll
  for (int r = 0; r < 4; ++r) inv[r] = 1.0f / lacc[r];
#pragma unroll
  for (int d4 = 0; d4 < 4; ++d4)
#pragma unroll
    for (int r = 0; r < 4; ++r) {
      const int q = qw0 + quad * 4 + r;
      y[(size_t)(b * T_SEQ + q) * DMODEL + h * DHEAD + d4 * 16 + l16] =
          f2bf(o[d4][r] * inv[r]);
    }
}

extern "C" void kernel_launch(void* const* d_in, const int* in_sizes, int n_in,
                              void* d_out, int out_size, void* d_ws, size_t ws_size,
                              hipStream_t stream) {
  const char* x = (const char*)d_in[0];       // [4,2048,1024] fp32 (or bf16)
  const char* w_qkv = (const char*)d_in[1];   // [1024,3072]
  const char* w_proj = (const char*)d_in[2];  // [1024,1024]
  const unsigned* xs = (const unsigned*)d_in[0];

  // ws: qk(33.6M) | vT(16.8M) | wqkvT(6.3M) | wprojT(2.1M) | xbf=ybuf(16.8M) = 75.5MB
  short* qk = (short*)d_ws;                          // 8192*2048
  short* vTb = qk + (size_t)8192 * 2048;             // 64*64*2048
  short* wqkvT = vTb + (size_t)64 * 64 * 2048;       // 3072*1024
  short* wprojT = wqkvT + (size_t)3072 * 1024;       // 1024*1024
  short* xbf = wprojT + (size_t)1024 * 1024;         // 8192*1024
  short* ybuf = xbf;                                 // alias: xbf dead after gemm1

  conv_x<<<8192 * 1024 / (256 * 8), 256, 0, stream>>>(x, xbf, 8192 * 1024, xs);
  {
    dim3 g1(3072 / 32, 1024 / 32);
    tpose<<<g1, 256, 0, stream>>>(w_qkv, wqkvT, 1024, 3072, xs);
    dim3 g2(1024 / 32, 1024 / 32);
    tpose<<<g2, 256, 0, stream>>>(w_proj, wprojT, 1024, 1024, xs);
  }
  {  // qkv projection with split epilogue: Q,K -> qk ; V -> vT (transposed)
    dim3 grid(3072 / 256, 8192 / 256);  // 12 x 32 = 384 blocks
    gemm256<<<grid, 512, 0, stream>>>(xbf, wqkvT, qk, vTb, 8192, 3072, 1024, 2, xs);
  }
  {
    dim3 grid(4 * NHEADS, T_SEQ / 64);
    attn<<<grid, 256, 0, stream>>>(qk, vTb, ybuf);
  }
  {  // proj: small grid (N=1024) -> 128^2 tile, 512 blocks, multi-block/CU
    dim3 grid(1024 / 128, 8192 / 128);
    gemm128<<<grid, 256, 0, stream>>>(ybuf, wprojT, d_out, nullptr, 8192, 1024, 1024, 1, xs);
  }
}

// Round 5
// 272.190 us; speedup vs baseline: 1.0431x; 1.0044x over previous
//
#include <hip/hip_runtime.h>
#include <hip/hip_bf16.h>
#include <cmath>

#define T_SEQ 2048
#define NHEADS 16
#define DHEAD 64
#define DMODEL 1024
#define CQKV 3072

typedef __attribute__((ext_vector_type(8))) short short8;
typedef __attribute__((ext_vector_type(8))) __bf16 bf16x8;
typedef __attribute__((ext_vector_type(4))) float floatx4;

#define LDS_CAST(p) ((__attribute__((address_space(3))) void*)(p))
#define GLB_CAST(p) ((const __attribute__((address_space(1))) void*)(p))

static __device__ __forceinline__ floatx4 mfma_bf16(short8 a, short8 b, floatx4 c) {
  return __builtin_amdgcn_mfma_f32_16x16x32_bf16(
      __builtin_bit_cast(bf16x8, a), __builtin_bit_cast(bf16x8, b), c, 0, 0, 0);
}

// fp32 -> bf16 round-to-nearest-even, bit carrier = short
static __device__ __forceinline__ short f2bf(float f) {
  union { float f; unsigned u; } x; x.f = f;
  unsigned r = x.u + 0x7FFFu + ((x.u >> 16) & 1u);
  return (short)(r >> 16);
}

static __device__ __forceinline__ float bf2f(short s) {
  return __builtin_bit_cast(float, ((unsigned)(unsigned short)s) << 16);
}

static __device__ __forceinline__ float exp2_(float x) {
#if __has_builtin(__builtin_amdgcn_exp2f)
  return __builtin_amdgcn_exp2f(x);
#else
  return exp2f(x);
#endif
}

// bf16 vs fp32 input sniff (round-1 notes). 16-of-32 exponent vote.
static __device__ __forceinline__ bool sniff_is_bf16(const unsigned* __restrict__ x) {
  int cnt = 0;
#pragma unroll
  for (int i = 0; i < 32; ++i) {
    unsigned e = (x[i] >> 7) & 0xFFu;
    cnt += (e >= 0x70u && e <= 0x8Fu) ? 1 : 0;
  }
  return cnt >= 16;
}

static __device__ __forceinline__ short8 load8f32(const char* p, size_t idx) {
  const float4* f = (const float4*)(p + idx * 4);
  float4 a = f[0], b = f[1];
  short8 r;
  r[0] = f2bf(a.x); r[1] = f2bf(a.y); r[2] = f2bf(a.z); r[3] = f2bf(a.w);
  r[4] = f2bf(b.x); r[5] = f2bf(b.y); r[6] = f2bf(b.z); r[7] = f2bf(b.w);
  return r;
}

// ---- preprocessing: x -> bf16 copy/convert --------------------------------
__global__ __launch_bounds__(256) void conv_x(const char* __restrict__ x,
                                              short* __restrict__ o, int n,
                                              const unsigned* __restrict__ xs) {
  const bool isbf = sniff_is_bf16(xs);
  const int i = (blockIdx.x * 256 + threadIdx.x) * 8;
  if (i >= n) return;
  if (isbf) *(short8*)(o + i) = *(const short8*)((const short*)x + i);
  else      *(short8*)(o + i) = load8f32(x, (size_t)i);
}

// ---- preprocessing: W [K][N] -> W^T [N][K] bf16 ---------------------------
__global__ __launch_bounds__(256) void tpose(const char* __restrict__ w,
                                             short* __restrict__ wt, int K, int N,
                                             const unsigned* __restrict__ xs) {
  const bool isbf = sniff_is_bf16(xs);
  __shared__ short tile[32][33];
  const int n0 = blockIdx.x * 32, k0 = blockIdx.y * 32;
  const int tx = threadIdx.x & 31, ty = threadIdx.x >> 5;  // 32 x 8
#pragma unroll
  for (int i = 0; i < 4; ++i) {
    const int r = ty * 4 + i;
    const size_t off = (size_t)(k0 + r) * N + n0 + tx;
    tile[r][tx] = isbf ? ((const short*)w)[off] : f2bf(((const float*)w)[off]);
  }
  __syncthreads();
#pragma unroll
  for (int i = 0; i < 4; ++i) {
    const int r = ty * 4 + i;
    wt[(size_t)(n0 + r) * K + k0 + tx] = tile[tx][r];
  }
}

// ---- GEMM (256x256, 8-phase counted-vmcnt, m201 template) -----------------
// Used ONLY where the grid is large enough (QKV: 384 blocks). Round-3/4
// measured: 85-87 us, MfmaUtil 24%, bank-conflict 0.
// mode 2: QKV split: cols [0,2048) -> qk [M,2048]; cols [2048,3072) -> vT.
__global__ __launch_bounds__(512) void gemm256(const short* __restrict__ A,
                                               const short* __restrict__ Bt,
                                               void* __restrict__ C,
                                               short* __restrict__ C2,
                                               int M, int N, int K, int mode,
                                               const unsigned* __restrict__ xs) {
  const bool out_f32 = (mode == 1) ? !sniff_is_bf16(xs) : false;

  __shared__ short as[2][256 * 64];  // 64 KiB
  __shared__ short bs[2][256 * 64];  // 64 KiB
  const int tid = threadIdx.x;
  const int wid = tid >> 6, lane = tid & 63;
  const int quad = lane >> 4, l16 = lane & 15;
  const int wm = wid >> 2, wn = wid & 3;  // 2 x 4 wave grid, each owns 128x64

  // XCD-aware bijective blockIdx swizzle (grids are multiples of 8)
  const int gx = (int)gridDim.x;
  const int nwg = gx * (int)gridDim.y;
  int bid = (int)blockIdx.y * gx + (int)blockIdx.x;
  bid = (bid & 7) * (nwg >> 3) + (bid >> 3);
  const int m0 = (bid / gx) * 256;
  const int n0 = (bid % gx) * 256;

  const int srl = lane >> 3;               // staging: row within 8-row group
  const int sch = ((lane & 7) ^ srl) * 8;  // XOR-swizzled source chunk (shorts)
  const int NT = K >> 6;

#define STAGE_A(t, h, b)                                                          \
  do {                                                                            \
    const int kt_ = (t) << 6;                                                     \
    _Pragma("unroll") for (int j_ = 0; j_ < 2; ++j_) {                            \
      const int row_ = (h) * 128 + j_ * 64 + wid * 8;                             \
      const short* g_ = A + (size_t)(m0 + row_ + srl) * K + kt_ + sch;            \
      __builtin_amdgcn_global_load_lds(GLB_CAST(g_), LDS_CAST(&as[(b)][row_ * 64]), 16, 0, 0); \
    }                                                                             \
  } while (0)

#define STAGE_B(t, h, b)                                                          \
  do {                                                                            \
    const int kt_ = (t) << 6;                                                     \
    _Pragma("unroll") for (int j_ = 0; j_ < 2; ++j_) {                            \
      const int row_ = (h) * 128 + j_ * 64 + wid * 8;                             \
      const short* g_ = Bt + (size_t)(n0 + row_ + srl) * K + kt_ + sch;           \
      __builtin_amdgcn_global_load_lds(GLB_CAST(g_), LDS_CAST(&bs[(b)][row_ * 64]), 16, 0, 0); \
    }                                                                             \
  } while (0)

#define SLOT_(kc) ((((kc) * 4 + quad) ^ (l16 & 7)) * 8)

#define LOAD_A(dst, mh, b)                                                        \
  do {                                                                            \
    _Pragma("unroll") for (int mf_ = 0; mf_ < 4; ++mf_)                           \
    _Pragma("unroll") for (int kc_ = 0; kc_ < 2; ++kc_)                           \
      dst[mf_][kc_] = *(const short8*)&as[(b)][(wm * 128 + (mh) * 64 + mf_ * 16 + l16) * 64 + SLOT_(kc_)]; \
  } while (0)

#define LOAD_B(dst, nh, b)                                                        \
  do {                                                                            \
    _Pragma("unroll") for (int nf_ = 0; nf_ < 2; ++nf_)                           \
    _Pragma("unroll") for (int kc_ = 0; kc_ < 2; ++kc_)                           \
      dst[nf_][kc_] = *(const short8*)&bs[(b)][(wn * 64 + (nh) * 32 + nf_ * 16 + l16) * 64 + SLOT_(kc_)]; \
  } while (0)

#define QMFMA(afrag, bfrag, mh, nh)                                               \
  do {                                                                            \
    __builtin_amdgcn_s_setprio(1);                                                \
    _Pragma("unroll") for (int mf_ = 0; mf_ < 4; ++mf_)                           \
    _Pragma("unroll") for (int nf_ = 0; nf_ < 2; ++nf_)                           \
    _Pragma("unroll") for (int kc_ = 0; kc_ < 2; ++kc_)                           \
      acc[(mh) * 4 + mf_][(nh) * 2 + nf_] =                                       \
          mfma_bf16(afrag[mf_][kc_], bfrag[nf_][kc_], acc[(mh) * 4 + mf_][(nh) * 2 + nf_]); \
    __builtin_amdgcn_s_setprio(0);                                                \
  } while (0)

  // pre-MFMA sync: barrier, then lgkm drain (doubles as code-motion fence)
#define BARW_()                                                                   \
  do {                                                                            \
    __builtin_amdgcn_s_barrier();                                                 \
    asm volatile("s_waitcnt lgkmcnt(0)" ::: "memory");                            \
  } while (0)

  const floatx4 zero4 = {0.f, 0.f, 0.f, 0.f};
  floatx4 acc[8][4];
#pragma unroll
  for (int i = 0; i < 8; ++i)
#pragma unroll
    for (int j = 0; j < 4; ++j) acc[i][j] = zero4;

  // ---- prologue: issue order must match steady-state so vmcnt counts work
  STAGE_B(0, 0, 0); STAGE_B(0, 1, 0);
  STAGE_A(0, 0, 0); STAGE_A(0, 1, 0);
  STAGE_B(1, 0, 1); STAGE_B(1, 1, 1);
  asm volatile("s_waitcnt vmcnt(4)" ::: "memory");  // tile0 landed; B(1) floats
  __builtin_amdgcn_s_barrier();

  short8 afr[4][2], bf0[2][2], bf1[2][2];

  for (int t = 0; t < NT; ++t) {
    const int cb = t & 1, nb = cb ^ 1;
    const int tA = (t + 1 < NT) ? t + 1 : NT - 1;  // clamped tail keeps vmcnt
    const int tB = (t + 2 < NT) ? t + 2 : NT - 1;  // counts uniform (junk-safe)

    // ---- phase 0: quadrant (mh0,nh0)
    LOAD_A(afr, 0, cb);
    LOAD_B(bf0, 0, cb);   // kept in regs through phase 3
    STAGE_A(tA, 0, nb);
    BARW_();
    QMFMA(afr, bf0, 0, 0);
    __builtin_amdgcn_s_barrier();

    // ---- phase 1: quadrant (mh0,nh1)
    LOAD_B(bf1, 1, cb);
    STAGE_A(tA, 1, nb);
    BARW_();
    QMFMA(afr, bf1, 0, 1);
    __builtin_amdgcn_s_barrier();

    // ---- phase 2: quadrant (mh1,nh1)
    LOAD_A(afr, 1, cb);
    STAGE_B(tB, 0, cb);   // cb's B fully read by end of phase 1
    BARW_();
    QMFMA(afr, bf1, 1, 1);
    __builtin_amdgcn_s_barrier();

    // ---- phase 3: quadrant (mh1,nh0) -- no ds_read, uses kept bf0
    STAGE_B(tB, 1, cb);
    asm volatile("s_waitcnt vmcnt(4)" ::: "memory");  // next tile confirmed
    BARW_();
    QMFMA(afr, bf0, 1, 0);
    __builtin_amdgcn_s_barrier();
  }
  // drain tail junk-stage DMAs before LDS can be handed to the next block
  asm volatile("s_waitcnt vmcnt(0)" ::: "memory");

  // ---- epilogue
  const int row0 = m0 + wm * 128 + quad * 4;
  const int col0 = n0 + wn * 64 + l16;
  if (mode == 2 && n0 >= 2048) {
    // V part -> transposed vT[(b*16+h)*64+d][t]
#pragma unroll
    for (int mi = 0; mi < 8; ++mi)
#pragma unroll
      for (int ni = 0; ni < 4; ++ni)
#pragma unroll
        for (int r = 0; r < 4; ++r) {
          const int row = row0 + mi * 16 + r;
          const int col = col0 + ni * 16;
          const int d = col & 63, hh = (col >> 6) - 32;
          const int bb = row >> 11, tq = row & 2047;
          C2[((size_t)(bb * 16 + hh) * 64 + d) * T_SEQ + tq] = f2bf(acc[mi][ni][r]);
        }
  } else {
    const int outN = (mode == 2) ? 2048 : N;
#pragma unroll
    for (int mi = 0; mi < 8; ++mi)
#pragma unroll
      for (int ni = 0; ni < 4; ++ni)
#pragma unroll
        for (int r = 0; r < 4; ++r) {
          const size_t off = (size_t)(row0 + mi * 16 + r) * outN + col0 + ni * 16;
          if (out_f32) ((float*)C)[off] = acc[mi][ni][r];
          else         ((short*)C)[off] = f2bf(acc[mi][ni][r]);
        }
  }
#undef STAGE_A
#undef STAGE_B
#undef SLOT_
#undef LOAD_A
#undef LOAD_B
#undef QMFMA
#undef BARW_
}

// ---- GEMM: 128x128 tile (round-0 verbatim) -- for small-grid GEMMs --------
// proj (N=1024): 512 blocks, 32 KiB LDS -> multi-block/CU.
__global__ __launch_bounds__(256) void gemm128(const short* __restrict__ A,
                                               const short* __restrict__ Bt,
                                               void* __restrict__ C,
                                               short* __restrict__ C2,
                                               int M, int N, int K, int mode,
                                               const unsigned* __restrict__ xs) {
  const bool out_f32 = (mode == 1) ? !sniff_is_bf16(xs) : false;

  __shared__ short as[128 * 64];
  __shared__ short bs[128 * 64];
  const int tid = threadIdx.x;
  const int wid = tid >> 6, lane = tid & 63;
  const int quad = lane >> 4, l16 = lane & 15;
  const int wm = wid >> 1, wn = wid & 1;
  const int m0 = blockIdx.y * 128, n0 = blockIdx.x * 128;

  const int srl = lane >> 3;               // row within the 8-row group
  const int sch = ((lane & 7) ^ srl) * 8;  // XOR-swizzled 16B chunk (shorts)

  const floatx4 zero4 = {0.f, 0.f, 0.f, 0.f};
  floatx4 acc[4][4];
#pragma unroll
  for (int i = 0; i < 4; ++i)
#pragma unroll
    for (int j = 0; j < 4; ++j) acc[i][j] = zero4;

  for (int kt = 0; kt < K; kt += 64) {
    __syncthreads();
#pragma unroll
    for (int i = 0; i < 4; ++i) {
      const int row = wid * 32 + i * 8;
      const short* ga = A + (size_t)(m0 + row + srl) * K + kt + sch;
      const short* gb = Bt + (size_t)(n0 + row + srl) * K + kt + sch;
      __builtin_amdgcn_global_load_lds(GLB_CAST(ga), LDS_CAST(as + row * 64), 16, 0, 0);
      __builtin_amdgcn_global_load_lds(GLB_CAST(gb), LDS_CAST(bs + row * 64), 16, 0, 0);
    }
    __syncthreads();

#pragma unroll
    for (int kc = 0; kc < 2; ++kc) {
      const int slot = ((kc * 4 + quad) ^ (l16 & 7)) * 8;
      short8 afr[4], bfr[4];
#pragma unroll
      for (int mt = 0; mt < 4; ++mt)
        afr[mt] = *(const short8*)&as[(wm * 64 + mt * 16 + l16) * 64 + slot];
#pragma unroll
      for (int nt = 0; nt < 4; ++nt)
        bfr[nt] = *(const short8*)&bs[(wn * 64 + nt * 16 + l16) * 64 + slot];
#pragma unroll
      for (int mt = 0; mt < 4; ++mt)
#pragma unroll
        for (int nt = 0; nt < 4; ++nt)
          acc[mt][nt] = mfma_bf16(afr[mt], bfr[nt], acc[mt][nt]);
    }
  }

  const int row0 = m0 + wm * 64 + quad * 4;
  const int col0 = n0 + wn * 64 + l16;
  if (mode == 2 && n0 >= 2048) {
#pragma unroll
    for (int mt = 0; mt < 4; ++mt)
#pragma unroll
      for (int nt = 0; nt < 4; ++nt)
#pragma unroll
        for (int r = 0; r < 4; ++r) {
          const int row = row0 + mt * 16 + r;
          const int col = col0 + nt * 16;
          const int d = col & 63, hh = (col >> 6) - 32;
          const int bb = row >> 11, t = row & 2047;
          C2[((size_t)(bb * 16 + hh) * 64 + d) * T_SEQ + t] = f2bf(acc[mt][nt][r]);
        }
  } else {
    const int outN = (mode == 2) ? 2048 : N;
#pragma unroll
    for (int mt = 0; mt < 4; ++mt)
#pragma unroll
      for (int nt = 0; nt < 4; ++nt)
#pragma unroll
        for (int r = 0; r < 4; ++r) {
          const size_t off = (size_t)(row0 + mt * 16 + r) * outN + col0 + nt * 16;
          if (out_f32) ((float*)C)[off] = acc[mt][nt][r];
          else         ((short*)C)[off] = f2bf(acc[mt][nt][r]);
        }
  }
}

// ---- flash attention (round-0 single-buffer version, reverted verbatim) ---
// Round-4 post-mortem: K/V dbuf raised LDS 25->41 KiB, dropping 6->3
// blocks/CU; TLP loss outweighed the halved barrier count (+20 us). attn's
// latency hiding comes from co-residency, not intra-block pipelining.
// qk [b*2048+t][2048] (Q cols 0..1023, K cols 1024..2047), vT [(b*16+h)*64+d][t].
// Block = 4 waves x 16 queries; BK=64. K/V tiles shared by all 4 waves.
__global__ __launch_bounds__(256) void attn(const short* __restrict__ qk,
                                            const short* __restrict__ vT,
                                            short* __restrict__ y) {
  __shared__ short ks[64 * 64];    // [key][d], 8 chunks/row XOR-swizzled
  __shared__ short vs[64 * 64];    // [d][key], same swizzle
  __shared__ short ps[4][16][72];  // per-wave P [q][key]
  const int tid = threadIdx.x;
  const int wid = tid >> 6, lane = tid & 63;
  const int quad = lane >> 4, l16 = lane & 15;
  const int b = blockIdx.x >> 4, h = blockIdx.x & 15;
  const int q0 = ((int)gridDim.y - 1 - (int)blockIdx.y) * 64;  // heavy blocks first
  const int qw0 = q0 + wid * 16;

  const short* qbase = qk + (size_t)b * T_SEQ * 2048 + h * DHEAD;
  const short* kbase = qbase + DMODEL;
  const short* vtb = vT + (size_t)(b * NHEADS + h) * DHEAD * T_SEQ;
  const float SC = 0.18033688011112042f;  // 0.125 * log2(e), folded into Q

  // Q fragments (A-layout m=l16, k=quad*8+j), pre-scaled by SC
  short8 aq[2];
#pragma unroll
  for (int kc = 0; kc < 2; ++kc) {
    short8 raw = *(const short8*)(qbase + (size_t)(qw0 + l16) * 2048 + kc * 32 + quad * 8);
#pragma unroll
    for (int j = 0; j < 8; ++j) aq[kc][j] = f2bf(bf2f(raw[j]) * SC);
  }

  const floatx4 zero4 = {0.f, 0.f, 0.f, 0.f};
  floatx4 o[4], lacc = zero4;  // lacc: row-sum via ones-MFMA
#pragma unroll
  for (int i = 0; i < 4; ++i) o[i] = zero4;
  const short8 ones8 = {0x3F80, 0x3F80, 0x3F80, 0x3F80, 0x3F80, 0x3F80, 0x3F80, 0x3F80};

  // staging lane map: row = i*32 + wid*8 + (lane>>3), chunk = (lane&7) ^ (row&7)
  const int srl = lane >> 3;
  const int sch = ((lane & 7) ^ srl) * 8;

  const int kend = q0 + 64;
  for (int kt = 0; kt < kend; kt += 64) {
    __syncthreads();  // prev iteration's LDS readers done
#pragma unroll
    for (int i = 0; i < 2; ++i) {
      const int row = i * 32 + wid * 8 + srl;
      const short* gk = kbase + (size_t)(kt + row) * 2048 + sch;
      const short* gv = vtb + (size_t)row * T_SEQ + kt + sch;
      __builtin_amdgcn_global_load_lds(GLB_CAST(gk), LDS_CAST(ks + (i * 32 + wid * 8) * 64), 16, 0, 0);
      __builtin_amdgcn_global_load_lds(GLB_CAST(gv), LDS_CAST(vs + (i * 32 + wid * 8) * 64), 16, 0, 0);
    }
    __syncthreads();  // DMA drained

    // S = Q K^T : 16q x 64key per wave; B-frag chunk kc*4+quad at swizzled slot
    floatx4 s[4];
#pragma unroll
    for (int nt = 0; nt < 4; ++nt) {
      s[nt] = zero4;
#pragma unroll
      for (int kc = 0; kc < 2; ++kc) {
        const int slot = ((kc * 4 + quad) ^ (l16 & 7)) * 8;
        const short8 bk = *(const short8*)&ks[(nt * 16 + l16) * 64 + slot];
        s[nt] = mfma_bf16(aq[kc], bk, s[nt]);
      }
    }

    // max-free softmax: p = 2^s; zero masked keys (diagonal tiles only)
    const bool full = (kt + 63 <= qw0);  // wave-uniform
#pragma unroll
    for (int nt = 0; nt < 4; ++nt)
#pragma unroll
      for (int r = 0; r < 4; ++r) {
        float p = exp2_(s[nt][r]);
        if (!full) {
          const int key = kt + nt * 16 + l16;
          const int q = qw0 + quad * 4 + r;
          p = (key <= q) ? p : 0.f;
        }
        s[nt][r] = p;
      }

    // P (C-layout) -> per-wave LDS [q][key] (wave-internal, no barrier)
#pragma unroll
    for (int nt = 0; nt < 4; ++nt)
#pragma unroll
      for (int r = 0; r < 4; ++r)
        ps[wid][quad * 4 + r][nt * 16 + l16] = f2bf(s[nt][r]);

    // O += P V ; l += P 1
#pragma unroll
    for (int kc = 0; kc < 2; ++kc) {
      const short8 ap = *(const short8*)&ps[wid][l16][kc * 32 + quad * 8];
      lacc = mfma_bf16(ap, ones8, lacc);
#pragma unroll
      for (int d4 = 0; d4 < 4; ++d4) {
        const int slot = ((kc * 4 + quad) ^ (l16 & 7)) * 8;
        const short8 bv = *(const short8*)&vs[(d4 * 16 + l16) * 64 + slot];
        o[d4] = mfma_bf16(ap, bv, o[d4]);
      }
    }
  }

  // epilogue: O /= l
  floatx4 inv;
#pragma unroll
  for (int r = 0; r < 4; ++r) inv[r] = 1.0f / lacc[r];
#pragma unroll
  for (int d4 = 0; d4 < 4; ++d4)
#pragma unroll
    for (int r = 0; r < 4; ++r) {
      const int q = qw0 + quad * 4 + r;
      y[(size_t)(b * T_SEQ + q) * DMODEL + h * DHEAD + d4 * 16 + l16] =
          f2bf(o[d4][r] * inv[r]);
    }
}

extern "C" void kernel_launch(void* const* d_in, const int* in_sizes, int n_in,
                              void* d_out, int out_size, void* d_ws, size_t ws_size,
                              hipStream_t stream) {
  const char* x = (const char*)d_in[0];       // [4,2048,1024] fp32 (or bf16)
  const char* w_qkv = (const char*)d_in[1];   // [1024,3072]
  const char* w_proj = (const char*)d_in[2];  // [1024,1024]
  const unsigned* xs = (const unsigned*)d_in[0];

  // ws: qk(33.6M) | vT(16.8M) | wqkvT(6.3M) | wprojT(2.1M) | xbf=ybuf(16.8M) = 75.5MB
  short* qk = (short*)d_ws;                          // 8192*2048
  short* vTb = qk + (size_t)8192 * 2048;             // 64*64*2048
  short* wqkvT = vTb + (size_t)64 * 64 * 2048;       // 3072*1024
  short* wprojT = wqkvT + (size_t)3072 * 1024;       // 1024*1024
  short* xbf = wprojT + (size_t)1024 * 1024;         // 8192*1024
  short* ybuf = xbf;                                 // alias: xbf dead after gemm1

  conv_x<<<8192 * 1024 / (256 * 8), 256, 0, stream>>>(x, xbf, 8192 * 1024, xs);
  {
    dim3 g1(3072 / 32, 1024 / 32);
    tpose<<<g1, 256, 0, stream>>>(w_qkv, wqkvT, 1024, 3072, xs);
    dim3 g2(1024 / 32, 1024 / 32);
    tpose<<<g2, 256, 0, stream>>>(w_proj, wprojT, 1024, 1024, xs);
  }
  {  // qkv projection with split epilogue: Q,K -> qk ; V -> vT (transposed)
    dim3 grid(3072 / 256, 8192 / 256);  // 12 x 32 = 384 blocks
    gemm256<<<grid, 512, 0, stream>>>(xbf, wqkvT, qk, vTb, 8192, 3072, 1024, 2, xs);
  }
  {
    dim3 grid(4 * NHEADS, T_SEQ / 64);
    attn<<<grid, 256, 0, stream>>>(qk, vTb, ybuf);
  }
  {  // proj: small grid (N=1024) -> 128^2 tile, 512 blocks, multi-block/CU
    dim3 grid(1024 / 128, 8192 / 128);
    gemm128<<<grid, 256, 0, stream>>>(ybuf, wprojT, d_out, nullptr, 8192, 1024, 1024, 1, xs);
  }
}

// Round 6
// 260.140 us; speedup vs baseline: 1.0914x; 1.0463x over previous
//
#include <hip/hip_runtime.h>
#include <hip/hip_bf16.h>
#include <cmath>

#define T_SEQ 2048
#define NHEADS 16
#define DHEAD 64
#define DMODEL 1024
#define CQKV 3072

typedef __attribute__((ext_vector_type(8))) short short8;
typedef __attribute__((ext_vector_type(8))) __bf16 bf16x8;
typedef __attribute__((ext_vector_type(4))) float floatx4;

#define LDS_CAST(p) ((__attribute__((address_space(3))) void*)(p))
#define GLB_CAST(p) ((const __attribute__((address_space(1))) void*)(p))

static __device__ __forceinline__ floatx4 mfma_bf16(short8 a, short8 b, floatx4 c) {
  return __builtin_amdgcn_mfma_f32_16x16x32_bf16(
      __builtin_bit_cast(bf16x8, a), __builtin_bit_cast(bf16x8, b), c, 0, 0, 0);
}

// fp32 -> bf16 round-to-nearest-even, bit carrier = short
static __device__ __forceinline__ short f2bf(float f) {
  union { float f; unsigned u; } x; x.f = f;
  unsigned r = x.u + 0x7FFFu + ((x.u >> 16) & 1u);
  return (short)(r >> 16);
}

static __device__ __forceinline__ float bf2f(short s) {
  return __builtin_bit_cast(float, ((unsigned)(unsigned short)s) << 16);
}

static __device__ __forceinline__ float exp2_(float x) {
#if __has_builtin(__builtin_amdgcn_exp2f)
  return __builtin_amdgcn_exp2f(x);
#else
  return exp2f(x);
#endif
}

// bf16 vs fp32 input sniff (round-1 notes). 16-of-32 exponent vote.
static __device__ __forceinline__ bool sniff_is_bf16(const unsigned* __restrict__ x) {
  int cnt = 0;
#pragma unroll
  for (int i = 0; i < 32; ++i) {
    unsigned e = (x[i] >> 7) & 0xFFu;
    cnt += (e >= 0x70u && e <= 0x8Fu) ? 1 : 0;
  }
  return cnt >= 16;
}

static __device__ __forceinline__ short8 load8f32(const char* p, size_t idx) {
  const float4* f = (const float4*)(p + idx * 4);
  float4 a = f[0], b = f[1];
  short8 r;
  r[0] = f2bf(a.x); r[1] = f2bf(a.y); r[2] = f2bf(a.z); r[3] = f2bf(a.w);
  r[4] = f2bf(b.x); r[5] = f2bf(b.y); r[6] = f2bf(b.z); r[7] = f2bf(b.w);
  return r;
}

// ---- fused preprocessing: conv_x + tpose(w_qkv) + tpose(w_proj) -----------
// One launch instead of three (saves 2 graph-replay gaps; fills the chip
// with all prep work at once). blockIdx.x ranges:
//   [0, 4096)            : x -> bf16 copy/convert (8 elems/thread)
//   [4096, 4096+3072)    : w_qkv [1024,3072] -> wqkvT [3072,1024]
//   [7168, 7168+1024)    : w_proj [1024,1024] -> wprojT [1024,1024]
__global__ __launch_bounds__(256) void prep(const char* __restrict__ x,
                                            short* __restrict__ xbf,
                                            const char* __restrict__ wqkv,
                                            short* __restrict__ wqkvT,
                                            const char* __restrict__ wproj,
                                            short* __restrict__ wprojT,
                                            const unsigned* __restrict__ xs) {
  const bool isbf = sniff_is_bf16(xs);
  const int bid = blockIdx.x;
  if (bid < 4096) {
    const int i = (bid * 256 + threadIdx.x) * 8;
    if (isbf) *(short8*)(xbf + i) = *(const short8*)((const short*)x + i);
    else      *(short8*)(xbf + i) = load8f32(x, (size_t)i);
    return;
  }
  // transpose part: 32x32 tile per block
  __shared__ short tile[32][33];
  const char* w; short* wt; int N, bid2;
  if (bid < 4096 + 3072) { w = wqkv;  wt = wqkvT;  N = 3072; bid2 = bid - 4096; }
  else                   { w = wproj; wt = wprojT; N = 1024; bid2 = bid - 7168; }
  const int K = 1024;
  const int ntiles = N >> 5;
  const int n0 = (bid2 % ntiles) * 32, k0 = (bid2 / ntiles) * 32;
  const int tx = threadIdx.x & 31, ty = threadIdx.x >> 5;  // 32 x 8
#pragma unroll
  for (int i = 0; i < 4; ++i) {
    const int r = ty * 4 + i;
    const size_t off = (size_t)(k0 + r) * N + n0 + tx;
    tile[r][tx] = isbf ? ((const short*)w)[off] : f2bf(((const float*)w)[off]);
  }
  __syncthreads();
#pragma unroll
  for (int i = 0; i < 4; ++i) {
    const int r = ty * 4 + i;
    wt[(size_t)(n0 + r) * K + k0 + tx] = tile[tx][r];
  }
}

// ---- GEMM: C = A @ Bt^T, 128x128 tile, BK=64, XOR-swizzled LDS ------------
// (round-0 verbatim; measured-best under bench conditions for BOTH QKV and
// proj -- the 256^2 8-phase variant profiles faster per-dispatch but is
// slower end-to-end: rocprof serializes at favorable clocks, bench doesn't.)
// BK=64 halves barrier count vs BK=32 (K=1024 -> 16 iters); LDS 32KB -> 5 blk/CU.
// mode 0: C bf16 row-major [M,N]
// mode 1: C dtype per sniff (bf16 in -> bf16 out, fp32 in -> fp32 out)
// mode 2: QKV split: cols [0,2048) -> qk [M,2048]; cols [2048,3072) -> vT.
__global__ __launch_bounds__(256) void gemm128(const short* __restrict__ A,
                                               const short* __restrict__ Bt,
                                               void* __restrict__ C,
                                               short* __restrict__ C2,
                                               int M, int N, int K, int mode,
                                               const unsigned* __restrict__ xs) {
  const bool out_f32 = (mode == 1) ? !sniff_is_bf16(xs) : false;

  __shared__ short as[128 * 64];
  __shared__ short bs[128 * 64];
  const int tid = threadIdx.x;
  const int wid = tid >> 6, lane = tid & 63;
  const int quad = lane >> 4, l16 = lane & 15;
  const int wm = wid >> 1, wn = wid & 1;
  const int m0 = blockIdx.y * 128, n0 = blockIdx.x * 128;

  // staging: issue i of wave covers rows wid*32 + i*8 .. +8 (128B rows)
  const int srl = lane >> 3;               // row within the 8-row group
  const int sch = ((lane & 7) ^ srl) * 8;  // XOR-swizzled 16B chunk (shorts)

  const floatx4 zero4 = {0.f, 0.f, 0.f, 0.f};
  floatx4 acc[4][4];
#pragma unroll
  for (int i = 0; i < 4; ++i)
#pragma unroll
    for (int j = 0; j < 4; ++j) acc[i][j] = zero4;

  for (int kt = 0; kt < K; kt += 64) {
    __syncthreads();
#pragma unroll
    for (int i = 0; i < 4; ++i) {
      const int row = wid * 32 + i * 8;
      const short* ga = A + (size_t)(m0 + row + srl) * K + kt + sch;
      const short* gb = Bt + (size_t)(n0 + row + srl) * K + kt + sch;
      __builtin_amdgcn_global_load_lds(GLB_CAST(ga), LDS_CAST(as + row * 64), 16, 0, 0);
      __builtin_amdgcn_global_load_lds(GLB_CAST(gb), LDS_CAST(bs + row * 64), 16, 0, 0);
    }
    __syncthreads();

    // fragment slot: chunk j of row R lives at slot j ^ (R&7); R&7 == l16&7
#pragma unroll
    for (int kc = 0; kc < 2; ++kc) {
      const int slot = ((kc * 4 + quad) ^ (l16 & 7)) * 8;
      short8 afr[4], bfr[4];
#pragma unroll
      for (int mt = 0; mt < 4; ++mt)
        afr[mt] = *(const short8*)&as[(wm * 64 + mt * 16 + l16) * 64 + slot];
#pragma unroll
      for (int nt = 0; nt < 4; ++nt)
        bfr[nt] = *(const short8*)&bs[(wn * 64 + nt * 16 + l16) * 64 + slot];
#pragma unroll
      for (int mt = 0; mt < 4; ++mt)
#pragma unroll
        for (int nt = 0; nt < 4; ++nt)
          acc[mt][nt] = mfma_bf16(afr[mt], bfr[nt], acc[mt][nt]);
    }
  }

  const int row0 = m0 + wm * 64 + quad * 4;
  const int col0 = n0 + wn * 64 + l16;
  if (mode == 2 && n0 >= 2048) {
    // V part -> transposed vT[(b*16+h)*64+d][t]
#pragma unroll
    for (int mt = 0; mt < 4; ++mt)
#pragma unroll
      for (int nt = 0; nt < 4; ++nt)
#pragma unroll
        for (int r = 0; r < 4; ++r) {
          const int row = row0 + mt * 16 + r;
          const int col = col0 + nt * 16;
          const int d = col & 63, hh = (col >> 6) - 32;
          const int bb = row >> 11, t = row & 2047;
          C2[((size_t)(bb * 16 + hh) * 64 + d) * T_SEQ + t] = f2bf(acc[mt][nt][r]);
        }
  } else {
    const int outN = (mode == 2) ? 2048 : N;
#pragma unroll
    for (int mt = 0; mt < 4; ++mt)
#pragma unroll
      for (int nt = 0; nt < 4; ++nt)
#pragma unroll
        for (int r = 0; r < 4; ++r) {
          const size_t off = (size_t)(row0 + mt * 16 + r) * outN + col0 + nt * 16;
          if (out_f32) ((float*)C)[off] = acc[mt][nt][r];
          else         ((short*)C)[off] = f2bf(acc[mt][nt][r]);
        }
  }
}

// ---- flash attention (round-0 single-buffer version, verbatim) ------------
// qk [b*2048+t][2048] (Q cols 0..1023, K cols 1024..2047), vT [(b*16+h)*64+d][t].
// Block = 4 waves x 16 queries; BK=64. K/V tiles shared by all 4 waves.
// 25.2 KiB LDS -> 6 blocks/CU; latency hiding via co-residency (round-4
// post-mortem: dbuf at 41 KiB / 3 blk/CU was ~neutral; keep simpler form).
__global__ __launch_bounds__(256) void attn(const short* __restrict__ qk,
                                            const short* __restrict__ vT,
                                            short* __restrict__ y) {
  __shared__ short ks[64 * 64];    // [key][d], 8 chunks/row XOR-swizzled
  __shared__ short vs[64 * 64];    // [d][key], same swizzle
  __shared__ short ps[4][16][72];  // per-wave P [q][key]
  const int tid = threadIdx.x;
  const int wid = tid >> 6, lane = tid & 63;
  const int quad = lane >> 4, l16 = lane & 15;
  const int b = blockIdx.x >> 4, h = blockIdx.x & 15;
  const int q0 = ((int)gridDim.y - 1 - (int)blockIdx.y) * 64;  // heavy blocks first
  const int qw0 = q0 + wid * 16;

  const short* qbase = qk + (size_t)b * T_SEQ * 2048 + h * DHEAD;
  const short* kbase = qbase + DMODEL;
  const short* vtb = vT + (size_t)(b * NHEADS + h) * DHEAD * T_SEQ;
  const float SC = 0.18033688011112042f;  // 0.125 * log2(e), folded into Q

  // Q fragments (A-layout m=l16, k=quad*8+j), pre-scaled by SC
  short8 aq[2];
#pragma unroll
  for (int kc = 0; kc < 2; ++kc) {
    short8 raw = *(const short8*)(qbase + (size_t)(qw0 + l16) * 2048 + kc * 32 + quad * 8);
#pragma unroll
    for (int j = 0; j < 8; ++j) aq[kc][j] = f2bf(bf2f(raw[j]) * SC);
  }

  const floatx4 zero4 = {0.f, 0.f, 0.f, 0.f};
  floatx4 o[4], lacc = zero4;  // lacc: row-sum via ones-MFMA
#pragma unroll
  for (int i = 0; i < 4; ++i) o[i] = zero4;
  const short8 ones8 = {0x3F80, 0x3F80, 0x3F80, 0x3F80, 0x3F80, 0x3F80, 0x3F80, 0x3F80};

  // staging lane map: row = i*32 + wid*8 + (lane>>3), chunk = (lane&7) ^ (row&7)
  const int srl = lane >> 3;
  const int sch = ((lane & 7) ^ srl) * 8;

  const int kend = q0 + 64;
  for (int kt = 0; kt < kend; kt += 64) {
    __syncthreads();  // prev iteration's LDS readers done
#pragma unroll
    for (int i = 0; i < 2; ++i) {
      const int row = i * 32 + wid * 8 + srl;
      const short* gk = kbase + (size_t)(kt + row) * 2048 + sch;
      const short* gv = vtb + (size_t)row * T_SEQ + kt + sch;
      __builtin_amdgcn_global_load_lds(GLB_CAST(gk), LDS_CAST(ks + (i * 32 + wid * 8) * 64), 16, 0, 0);
      __builtin_amdgcn_global_load_lds(GLB_CAST(gv), LDS_CAST(vs + (i * 32 + wid * 8) * 64), 16, 0, 0);
    }
    __syncthreads();  // DMA drained

    // S = Q K^T : 16q x 64key per wave; B-frag chunk kc*4+quad at swizzled slot
    floatx4 s[4];
#pragma unroll
    for (int nt = 0; nt < 4; ++nt) {
      s[nt] = zero4;
#pragma unroll
      for (int kc = 0; kc < 2; ++kc) {
        const int slot = ((kc * 4 + quad) ^ (l16 & 7)) * 8;
        const short8 bk = *(const short8*)&ks[(nt * 16 + l16) * 64 + slot];
        s[nt] = mfma_bf16(aq[kc], bk, s[nt]);
      }
    }

    // max-free softmax: p = 2^s; zero masked keys (diagonal tiles only)
    const bool full = (kt + 63 <= qw0);  // wave-uniform
#pragma unroll
    for (int nt = 0; nt < 4; ++nt)
#pragma unroll
      for (int r = 0; r < 4; ++r) {
        float p = exp2_(s[nt][r]);
        if (!full) {
          const int key = kt + nt * 16 + l16;
          const int q = qw0 + quad * 4 + r;
          p = (key <= q) ? p : 0.f;
        }
        s[nt][r] = p;
      }

    // P (C-layout) -> per-wave LDS [q][key] (wave-internal, no barrier)
#pragma unroll
    for (int nt = 0; nt < 4; ++nt)
#pragma unroll
      for (int r = 0; r < 4; ++r)
        ps[wid][quad * 4 + r][nt * 16 + l16] = f2bf(s[nt][r]);

    // O += P V ; l += P 1
#pragma unroll
    for (int kc = 0; kc < 2; ++kc) {
      const short8 ap = *(const short8*)&ps[wid][l16][kc * 32 + quad * 8];
      lacc = mfma_bf16(ap, ones8, lacc);
#pragma unroll
      for (int d4 = 0; d4 < 4; ++d4) {
        const int slot = ((kc * 4 + quad) ^ (l16 & 7)) * 8;
        const short8 bv = *(const short8*)&vs[(d4 * 16 + l16) * 64 + slot];
        o[d4] = mfma_bf16(ap, bv, o[d4]);
      }
    }
  }

  // epilogue: O /= l
  floatx4 inv;
#pragma unroll
  for (int r = 0; r < 4; ++r) inv[r] = 1.0f / lacc[r];
#pragma unroll
  for (int d4 = 0; d4 < 4; ++d4)
#pragma unroll
    for (int r = 0; r < 4; ++r) {
      const int q = qw0 + quad * 4 + r;
      y[(size_t)(b * T_SEQ + q) * DMODEL + h * DHEAD + d4 * 16 + l16] =
          f2bf(o[d4][r] * inv[r]);
    }
}

extern "C" void kernel_launch(void* const* d_in, const int* in_sizes, int n_in,
                              void* d_out, int out_size, void* d_ws, size_t ws_size,
                              hipStream_t stream) {
  const char* x = (const char*)d_in[0];       // [4,2048,1024] fp32 (or bf16)
  const char* w_qkv = (const char*)d_in[1];   // [1024,3072]
  const char* w_proj = (const char*)d_in[2];  // [1024,1024]
  const unsigned* xs = (const unsigned*)d_in[0];

  // ws: qk(33.6M) | vT(16.8M) | wqkvT(6.3M) | wprojT(2.1M) | xbf=ybuf(16.8M) = 75.5MB
  short* qk = (short*)d_ws;                          // 8192*2048
  short* vTb = qk + (size_t)8192 * 2048;             // 64*64*2048
  short* wqkvT = vTb + (size_t)64 * 64 * 2048;       // 3072*1024
  short* wprojT = wqkvT + (size_t)3072 * 1024;       // 1024*1024
  short* xbf = wprojT + (size_t)1024 * 1024;         // 8192*1024
  short* ybuf = xbf;                                 // alias: xbf dead after gemm1

  // fused prep: conv_x (4096 blocks) + tpose wqkv (3072) + tpose wproj (1024)
  prep<<<4096 + 3072 + 1024, 256, 0, stream>>>(x, xbf, w_qkv, wqkvT, w_proj, wprojT, xs);
  {  // qkv projection with split epilogue: Q,K -> qk ; V -> vT (transposed)
    dim3 grid(3072 / 128, 8192 / 128);
    gemm128<<<grid, 256, 0, stream>>>(xbf, wqkvT, qk, vTb, 8192, 3072, 1024, 2, xs);
  }
  {
    dim3 grid(4 * NHEADS, T_SEQ / 64);
    attn<<<grid, 256, 0, stream>>>(qk, vTb, ybuf);
  }
  {
    dim3 grid(1024 / 128, 8192 / 128);
    gemm128<<<grid, 256, 0, stream>>>(ybuf, wprojT, d_out, nullptr, 8192, 1024, 1024, 1, xs);
  }
}